// Round 13
// baseline (72.679 us; speedup 1.0000x reference)
//
#include <hip/hip_runtime.h>
#include <hip/hip_bf16.h>
#include <math.h>

// SparseFlashAttention: B=2, S=2048, H=16, D=64, fp32 in/out, [S,S] bool mask.
#define SLEN 2048
#define NBATCH 2
#define NH 16
#define DH 64
#define WPR 64      // mask words per row
#define NROUND 32   // 64-key rounds
#define TILEB 16384 // bytes per 64-key fragment-image tile (K frags 0-7, V frags 8-15)
#define CONVBLK (NBATCH * NH * NROUND)          // 1024 conv blocks
#define PACKBLK (SLEN * WPR / 256)              // 512 pack blocks

typedef __attribute__((ext_vector_type(4))) short short4v;
typedef __attribute__((ext_vector_type(8))) short short8v;
typedef __attribute__((ext_vector_type(4))) float float4v;
typedef __attribute__((ext_vector_type(16))) float float16v;

__device__ __forceinline__ unsigned short f2bf(float f) {
  unsigned u = __float_as_uint(f);
  u += 0x7fffu + ((u >> 16) & 1u);
  return (unsigned short)(u >> 16);
}

__device__ __forceinline__ float fexp2(float x) {
#if __has_builtin(__builtin_amdgcn_exp2f)
  return __builtin_amdgcn_exp2f(x);
#else
  return __expf(x * 0.6931471805599453f);
#endif
}

// RNE pack via integer ops (prep/Q path)
__device__ __forceinline__ unsigned pack_bf2(float a, float b) {
  unsigned ua = __float_as_uint(a); ua += 0x7fffu + ((ua >> 16) & 1u);
  unsigned ub = __float_as_uint(b); ub += 0x7fffu + ((ub >> 16) & 1u);
  return __builtin_amdgcn_perm(ub, ua, 0x07060302u);
}

// HW packed f32->bf16x2: dst[15:0]=bf16(lo), dst[31:16]=bf16(hi). 1 VALU op.
__device__ __forceinline__ unsigned cvtpk(float lo, float hi) {
  unsigned r;
  asm("v_cvt_pk_bf16_f32 %0, %1, %2" : "=v"(r) : "v"(lo), "v"(hi));
  return r;
}

// bool-byte word (bytes in {0,1}) -> 4-bit nibble, bit j = byte j
__device__ __forceinline__ unsigned nib4(unsigned w) {
  return ((w * 0x01020408u) >> 24) & 0xFu;
}

// ---------------------------------------------------------------------------
// Fragment-image layout (verified R9): tile (bh, t) = 16 frags x 1024 B.
// Lane l of frag i reads bytes [i*1024 + l*16, +16) -- coalesced per wave.
//   K element (key r, dim d):  frag = (r>>5)*4 + (d>>4);
//     lane = ((d>>3)&1)*32 + (r&31); byte slot = (d&7)*2.
//   V element (key p, dim d):  frag = 8 + (d>>5)*4 + 2*(p>>5) + ((p>>4)&1);
//     lane = ((p>>2)&1)*32 + (d&31); slot = (4*((p>>3)&1) + (p&3))*2.
// ---------------------------------------------------------------------------
__global__ __launch_bounds__(256) void prep_kernel(
    const float* __restrict__ kk, const float* __restrict__ vv,
    const void* __restrict__ mask,
    char* __restrict__ img, unsigned* __restrict__ packed, int convblocks) {
  const int tid = threadIdx.x;
  if (blockIdx.x >= convblocks) {  // ---- mask pack with block-local self-detect
    const int w = (blockIdx.x - convblocks) * 256 + tid;
    const uint4* bp = (const uint4*)((const char*)mask + (size_t)w * 32);
    uint4 x = bp[0], y = bp[1];
    const unsigned orw = (x.x | x.y) | (x.z | x.w) | (y.x | y.y) | (y.z | y.w);
    __shared__ int s0, sm;
    if (tid == 0) { s0 = 0; sm = 0; }
    __syncthreads();
    const int lane0 = ((tid & 63) == 0);
    if (__any((orw & 0x000000ffu) != 0) && lane0) atomicOr(&s0, 1);
    if (__any((orw & 0xffffff00u) != 0) && lane0) atomicOr(&sm, 1);
    __syncthreads();
    unsigned bits;
    if (s0 && sm) {  // byte bools
      bits = nib4(x.x) | (nib4(x.y) << 4) | (nib4(x.z) << 8) | (nib4(x.w) << 12) |
             (nib4(y.x) << 16) | (nib4(y.y) << 20) | (nib4(y.z) << 24) | (nib4(y.w) << 28);
    } else {  // 32-bit words
      const unsigned* m = (const unsigned*)mask + (size_t)w * 32;
      bits = 0u;
#pragma unroll
      for (int j = 0; j < 32; j++) bits |= (m[j] ? 1u : 0u) << j;
    }
    packed[w] = bits;
    return;
  }
  // ---- conv (fragment images)
  const int bid = blockIdx.x;  // bh*32 + t
  const int t = bid & 31;
  const int bh = bid >> 5;
  const int b = bh >> 4, h = bh & 15;
  char* timg = img + (size_t)bid * TILEB;

  {  // K: thread -> (key r, 16-dim group dg); two 16B contiguous writes
    const int r = tid >> 2;
    const int dg = (tid & 3) << 4;
    const float* src = kk + (((size_t)(b * SLEN + t * 64 + r) * NH + h) * DH + dg);
    const int f = ((r >> 5) << 2) + (dg >> 4);
    char* base = timg + f * 1024 + (r & 31) * 16;  // hl=0 slot; hl=1 at +512
    float4v x0 = *(const float4v*)(src);
    float4v x1 = *(const float4v*)(src + 4);
    float4v x2 = *(const float4v*)(src + 8);
    float4v x3 = *(const float4v*)(src + 12);
    union { unsigned u[4]; short8v s8; } lo, hi;
    lo.u[0] = pack_bf2(x0.x, x0.y); lo.u[1] = pack_bf2(x0.z, x0.w);
    lo.u[2] = pack_bf2(x1.x, x1.y); lo.u[3] = pack_bf2(x1.z, x1.w);
    hi.u[0] = pack_bf2(x2.x, x2.y); hi.u[1] = pack_bf2(x2.z, x2.w);
    hi.u[2] = pack_bf2(x3.x, x3.y); hi.u[3] = pack_bf2(x3.z, x3.w);
    *(short8v*)(base) = lo.s8;
    *(short8v*)(base + 512) = hi.s8;
  }
  {  // V: thread -> (dim d, 16-key group kg); 2B transposed scatter
    const int d = tid >> 2;
    const int kg = (tid & 3) << 4;
    const float* src = vv + ((size_t)(b * SLEN + t * 64 + kg) * NH + h) * DH + d;
    const int fbase = 8 + ((d >> 5) << 2);
    const int l31d = d & 31;
#pragma unroll
    for (int i = 0; i < 16; i++) {
      const int p = kg + i;
      float x = src[(size_t)i * (NH * DH)];
      const int f = fbase + 2 * (p >> 5) + ((p >> 4) & 1);
      const int lane = ((p >> 2) & 1) * 32 + l31d;
      const int slot = 4 * ((p >> 3) & 1) + (p & 3);
      *(unsigned short*)(timg + f * 1024 + lane * 16 + slot * 2) = f2bf(x);
    }
  }
}

// ---------------------------------------------------------------------------
// Main kernel R13: R9 structure verbatim (no LDS, no barriers, 512 blocks x
// 4 waves, 32 rounds, verified bit-mask softmax) + two zero-layout-risk
// changes: (a) l accumulated by ones-MFMA (R8-verified pattern: ones A-frag x
// pf B-frag, lacc[0] epilogue) removing 32 VALU adds/round + the epilogue
// shuffle; (b) 4 base pointers so all 16 fragment loads use immediate
// offsets (no per-load 64-bit address adds). R12's emask path abandoned
// (failed correctness; bug not identified by inspection).
// ---------------------------------------------------------------------------
__global__ __launch_bounds__(256, 2) void sattn_fast12(
    const float* __restrict__ q, const unsigned* __restrict__ pmask,
    const char* __restrict__ img, float* __restrict__ out) {
  const int tid = threadIdx.x;
  const int xcd = blockIdx.x & 7;
  const int j = blockIdx.x >> 3;            // 0..63
  const int bh = xcd * 4 + (j >> 4);        // 4 bh per XCD -> images L2-resident
  const int chunk = j & 15;                 // 16 chunks of 128 queries
  const int b = bh >> 4;
  const int hd = bh & 15;
  const int wave = tid >> 6;
  const int lane = tid & 63;
  const int l31 = lane & 31;
  const int hl = lane >> 5;

  const int qrow = chunk * 128 + wave * 32 + l31;
  const int qw = qrow * WPR;

  // Q B-frags, pre-scaled by (1/sqrt(64))*log2(e); qf[ds] elem j = Q[q][16ds+8hl+j]
  const float SCL2 = 0.18033688011112042f;
  short8v qf[4];
  {
    const float* qp = q + (((size_t)b * SLEN + qrow) * NH + hd) * DH;
#pragma unroll
    for (int ds = 0; ds < 4; ds++) {
      float4v x0 = *(const float4v*)(qp + ds * 16 + hl * 8);
      float4v x1 = *(const float4v*)(qp + ds * 16 + hl * 8 + 4);
      union { unsigned u[4]; short8v s8; } cv;
      cv.u[0] = pack_bf2(x0.x * SCL2, x0.y * SCL2);
      cv.u[1] = pack_bf2(x0.z * SCL2, x0.w * SCL2);
      cv.u[2] = pack_bf2(x1.x * SCL2, x1.y * SCL2);
      cv.u[3] = pack_bf2(x1.z * SCL2, x1.w * SCL2);
      qf[ds] = cv.s8;
    }
  }

  // all-ones A-frag (bf16 1.0) for the l-accumulating MFMA (R8-verified)
  short8v ones;
#pragma unroll
  for (int i = 0; i < 8; i++) ones[i] = (short)0x3F80;

  // 4 fragment base pointers (imm offsets 0..3072 within each)
  const char* fb0 = img + (size_t)bh * (NROUND * TILEB) + lane * 16;
  const char* fb1 = fb0 + 4096;
  const char* fb2 = fb0 + 8192;
  const char* fb3 = fb0 + 12288;

  float16v acc0 = {}, acc1 = {}, lacc = {};

  // prologue: round-0 fragments + mask
  short8v kf0 = *(const short8v*)(fb0 + 0);
  short8v kf1 = *(const short8v*)(fb0 + 1024);
  short8v kf2 = *(const short8v*)(fb0 + 2048);
  short8v kf3 = *(const short8v*)(fb0 + 3072);
  short8v kf4 = *(const short8v*)(fb1 + 0);
  short8v kf5 = *(const short8v*)(fb1 + 1024);
  short8v kf6 = *(const short8v*)(fb1 + 2048);
  short8v kf7 = *(const short8v*)(fb1 + 3072);
  short8v vf0 = *(const short8v*)(fb2 + 0);
  short8v vf1 = *(const short8v*)(fb2 + 1024);
  short8v vf2 = *(const short8v*)(fb2 + 2048);
  short8v vf3 = *(const short8v*)(fb2 + 3072);
  short8v vf4 = *(const short8v*)(fb3 + 0);
  short8v vf5 = *(const short8v*)(fb3 + 1024);
  short8v vf6 = *(const short8v*)(fb3 + 2048);
  short8v vf7 = *(const short8v*)(fb3 + 3072);
  uint2 m = *(const uint2*)&pmask[qw];

  for (int t = 0; t < NROUND; t++) {
    const unsigned m0 = m.x, m1 = m.y;
    const int tn = (t + 1 < NROUND) ? t + 1 : t;  // last-iter reload harmless

    // ---- QK^T: st0 = keys 0..31, st1 = keys 32..63 of this tile
    __builtin_amdgcn_s_setprio(1);
    float16v st0 = {}, st1 = {};
    st0 = __builtin_amdgcn_mfma_f32_32x32x16_bf16(kf0, qf[0], st0, 0, 0, 0);
    st1 = __builtin_amdgcn_mfma_f32_32x32x16_bf16(kf4, qf[0], st1, 0, 0, 0);
    st0 = __builtin_amdgcn_mfma_f32_32x32x16_bf16(kf1, qf[1], st0, 0, 0, 0);
    st1 = __builtin_amdgcn_mfma_f32_32x32x16_bf16(kf5, qf[1], st1, 0, 0, 0);
    st0 = __builtin_amdgcn_mfma_f32_32x32x16_bf16(kf2, qf[2], st0, 0, 0, 0);
    st1 = __builtin_amdgcn_mfma_f32_32x32x16_bf16(kf6, qf[2], st1, 0, 0, 0);
    st0 = __builtin_amdgcn_mfma_f32_32x32x16_bf16(kf3, qf[3], st0, 0, 0, 0);
    st1 = __builtin_amdgcn_mfma_f32_32x32x16_bf16(kf7, qf[3], st1, 0, 0, 0);
    __builtin_amdgcn_s_setprio(0);

    // ---- advance bases (clamped on last round) + reload K/mask for t+1
    const int adv = (tn != t) ? TILEB : 0;
    fb0 += adv; fb1 += adv; fb2 += adv; fb3 += adv;
    kf0 = *(const short8v*)(fb0 + 0);
    kf1 = *(const short8v*)(fb0 + 1024);
    kf2 = *(const short8v*)(fb0 + 2048);
    kf3 = *(const short8v*)(fb0 + 3072);
    kf4 = *(const short8v*)(fb1 + 0);
    kf5 = *(const short8v*)(fb1 + 1024);
    kf6 = *(const short8v*)(fb1 + 2048);
    kf7 = *(const short8v*)(fb1 + 3072);
    m = *(const uint2*)&pmask[qw + 2 * tn];

    // ---- softmax + mask + pack (R9-verified bit-mask path)
    // reg r of st_h <-> key 32h + (r&3) + 8*(r>>2) + 4*hl
    float p0[16], p1[16];
#pragma unroll
    for (int u = 0; u < 4; u++) {
      const unsigned hw0 = m0 >> (8 * u + 4 * hl);
      const unsigned hw1 = m1 >> (8 * u + 4 * hl);
      {
        float a0 = fexp2(st0[4 * u + 0]); a0 = (hw0 & 1u) ? a0 : 0.f;
        float a1 = fexp2(st0[4 * u + 1]); a1 = (hw0 & 2u) ? a1 : 0.f;
        float a2 = fexp2(st0[4 * u + 2]); a2 = (hw0 & 4u) ? a2 : 0.f;
        float a3 = fexp2(st0[4 * u + 3]); a3 = (hw0 & 8u) ? a3 : 0.f;
        p0[4 * u + 0] = a0; p0[4 * u + 1] = a1; p0[4 * u + 2] = a2; p0[4 * u + 3] = a3;
      }
      {
        float a0 = fexp2(st1[4 * u + 0]); a0 = (hw1 & 1u) ? a0 : 0.f;
        float a1 = fexp2(st1[4 * u + 1]); a1 = (hw1 & 2u) ? a1 : 0.f;
        float a2 = fexp2(st1[4 * u + 2]); a2 = (hw1 & 4u) ? a2 : 0.f;
        float a3 = fexp2(st1[4 * u + 3]); a3 = (hw1 & 8u) ? a3 : 0.f;
        p1[4 * u + 0] = a0; p1[4 * u + 1] = a1; p1[4 * u + 2] = a2; p1[4 * u + 3] = a3;
      }
    }
    // pf[kc] = B-frag of key-group kc: slot j = C/D reg 8*(kc&1)+j of st[kc>>1]
    short8v pf0, pf1, pf2, pf3;
    {
      union { unsigned u[4]; short8v s8; } c0, c1, c2, c3;
#pragma unroll
      for (int jj = 0; jj < 4; jj++) {
        c0.u[jj] = cvtpk(p0[2 * jj], p0[2 * jj + 1]);
        c1.u[jj] = cvtpk(p0[8 + 2 * jj], p0[8 + 2 * jj + 1]);
        c2.u[jj] = cvtpk(p1[2 * jj], p1[2 * jj + 1]);
        c3.u[jj] = cvtpk(p1[8 + 2 * jj], p1[8 + 2 * jj + 1]);
      }
      pf0 = c0.s8; pf1 = c1.s8; pf2 = c2.s8; pf3 = c3.s8;
    }

    // ---- PV + ones-l (V-frag kc for d-half n: vf[n*4+kc])
    __builtin_amdgcn_s_setprio(1);
    acc0 = __builtin_amdgcn_mfma_f32_32x32x16_bf16(vf0, pf0, acc0, 0, 0, 0);
    acc1 = __builtin_amdgcn_mfma_f32_32x32x16_bf16(vf4, pf0, acc1, 0, 0, 0);
    lacc = __builtin_amdgcn_mfma_f32_32x32x16_bf16(ones, pf0, lacc, 0, 0, 0);
    acc0 = __builtin_amdgcn_mfma_f32_32x32x16_bf16(vf1, pf1, acc0, 0, 0, 0);
    acc1 = __builtin_amdgcn_mfma_f32_32x32x16_bf16(vf5, pf1, acc1, 0, 0, 0);
    lacc = __builtin_amdgcn_mfma_f32_32x32x16_bf16(ones, pf1, lacc, 0, 0, 0);
    acc0 = __builtin_amdgcn_mfma_f32_32x32x16_bf16(vf2, pf2, acc0, 0, 0, 0);
    acc1 = __builtin_amdgcn_mfma_f32_32x32x16_bf16(vf6, pf2, acc1, 0, 0, 0);
    lacc = __builtin_amdgcn_mfma_f32_32x32x16_bf16(ones, pf2, lacc, 0, 0, 0);
    acc0 = __builtin_amdgcn_mfma_f32_32x32x16_bf16(vf3, pf3, acc0, 0, 0, 0);
    acc1 = __builtin_amdgcn_mfma_f32_32x32x16_bf16(vf7, pf3, acc1, 0, 0, 0);
    lacc = __builtin_amdgcn_mfma_f32_32x32x16_bf16(ones, pf3, lacc, 0, 0, 0);
    __builtin_amdgcn_s_setprio(0);

    // ---- reload V for t+1
    vf0 = *(const short8v*)(fb2 + 0);
    vf1 = *(const short8v*)(fb2 + 1024);
    vf2 = *(const short8v*)(fb2 + 2048);
    vf3 = *(const short8v*)(fb2 + 3072);
    vf4 = *(const short8v*)(fb3 + 0);
    vf5 = *(const short8v*)(fb3 + 1024);
    vf6 = *(const short8v*)(fb3 + 2048);
    vf7 = *(const short8v*)(fb3 + 3072);
  }

  // lacc rows identical: ones-MFMA contracts ALL 16 k-slots (both hl halves),
  // so lacc[0] = full denominator for q = l31 (R8-verified; no shuffle).
  const float l = lacc[0];
  const float inv = (l > 0.f) ? 1.f / l : 0.f;
  float* op = out + (((size_t)b * SLEN + qrow) * NH + hd) * DH;
#pragma unroll
  for (int u = 0; u < 4; u++) {
    float4v o0, o1;
    o0.x = acc0[4 * u + 0] * inv; o0.y = acc0[4 * u + 1] * inv;
    o0.z = acc0[4 * u + 2] * inv; o0.w = acc0[4 * u + 3] * inv;
    o1.x = acc1[4 * u + 0] * inv; o1.y = acc1[4 * u + 1] * inv;
    o1.z = acc1[4 * u + 2] * inv; o1.w = acc1[4 * u + 3] * inv;
    *(float4v*)(op + 8 * u + 4 * hl) = o0;
    *(float4v*)(op + 32 + 8 * u + 4 * hl) = o1;
  }
}

// ---------------------------------------------------------------------------
// Fallback (R1 kernel, verified): used only if ws_size can't hold the images.
// ---------------------------------------------------------------------------
__global__ __launch_bounds__(256) void sattn_fallback(
    const float* __restrict__ q, const float* __restrict__ kk,
    const float* __restrict__ vv, const unsigned int* __restrict__ pmask,
    float* __restrict__ out) {
  __shared__ __align__(16) unsigned short Kt[16 * 64];
  __shared__ __align__(16) unsigned short Vt[64 * 20];

  const int tid = threadIdx.x;
  const int chunk = blockIdx.x & 31;
  const int bh = blockIdx.x >> 5;
  const int b = bh >> 4;
  const int h = bh & 15;
  const int wave = tid >> 6;
  const int lane = tid & 63;
  const int lq = lane & 15;
  const int g = lane >> 4;

  const int qrow = chunk * 64 + wave * 16 + lq;

  short4v qf[4];
  {
    const float* qp = q + (((size_t)b * SLEN + qrow) * NH + h) * DH;
#pragma unroll
    for (int ks = 0; ks < 4; ks++) {
      float4v x = *(const float4v*)(qp + ks * 16 + g * 4);
      short4v s;
      s.x = (short)f2bf(x.x); s.y = (short)f2bf(x.y);
      s.z = (short)f2bf(x.z); s.w = (short)f2bf(x.w);
      qf[ks] = s;
    }
  }

  const int srow = tid >> 4;
  const int scol = (tid & 15) * 4;
  const size_t kvbase = (size_t)b * SLEN * (NH * DH) + (size_t)h * DH;

  float4v acc[4] = {};
  float m_run = -INFINITY;
  float l_run = 0.f;

  for (int t = 0; t < SLEN / 16; t++) {
    const int kbase = t * 16;
    __syncthreads();
    {
      const size_t rowoff = kvbase + (size_t)(kbase + srow) * (NH * DH) + scol;
      float4v x = *(const float4v*)(kk + rowoff);
      short4v s;
      s.x = (short)f2bf(x.x); s.y = (short)f2bf(x.y);
      s.z = (short)f2bf(x.z); s.w = (short)f2bf(x.w);
      const int off = (scol * 2) ^ ((srow & 7) << 4);
      *(short4v*)((char*)Kt + srow * 128 + off) = s;

      float4v y = *(const float4v*)(vv + rowoff);
      Vt[(scol + 0) * 20 + srow] = f2bf(y.x);
      Vt[(scol + 1) * 20 + srow] = f2bf(y.y);
      Vt[(scol + 2) * 20 + srow] = f2bf(y.z);
      Vt[(scol + 3) * 20 + srow] = f2bf(y.w);
    }
    __syncthreads();

    float4v stv = {0.f, 0.f, 0.f, 0.f};
#pragma unroll
    for (int ks = 0; ks < 4; ks++) {
      const int off = ((ks * 16 + g * 4) * 2) ^ ((lq & 7) << 4);
      short4v kf = *(const short4v*)((const char*)Kt + lq * 128 + off);
      stv = __builtin_amdgcn_mfma_f32_16x16x16bf16_1k(kf, qf[ks], stv, 0, 0, 0);
    }

    const unsigned int mw = pmask[qrow * WPR + (kbase >> 5)];
    const int shift = (kbase & 16) + g * 4;
    float sc[4];
    float tmax = -INFINITY;
#pragma unroll
    for (int r = 0; r < 4; r++) {
      bool a = (mw >> (shift + r)) & 1u;
      sc[r] = a ? stv[r] * 0.125f : -INFINITY;
      tmax = fmaxf(tmax, sc[r]);
    }
    tmax = fmaxf(tmax, __shfl_xor(tmax, 16));
    tmax = fmaxf(tmax, __shfl_xor(tmax, 32));
    const float mnew = fmaxf(m_run, tmax);
    const float muse = (mnew > -1e37f) ? mnew : 0.f;
    const float alpha = __expf(m_run - muse);
    float p[4], tsum = 0.f;
#pragma unroll
    for (int r = 0; r < 4; r++) {
      p[r] = __expf(sc[r] - muse);
      tsum += p[r];
    }
    tsum += __shfl_xor(tsum, 16);
    tsum += __shfl_xor(tsum, 32);
    l_run = l_run * alpha + tsum;
    m_run = mnew;

    short4v pfv;
    pfv.x = (short)f2bf(p[0]); pfv.y = (short)f2bf(p[1]);
    pfv.z = (short)f2bf(p[2]); pfv.w = (short)f2bf(p[3]);

#pragma unroll
    for (int n = 0; n < 4; n++) {
      acc[n][0] *= alpha; acc[n][1] *= alpha;
      acc[n][2] *= alpha; acc[n][3] *= alpha;
      short4v vf = *(const short4v*)((const char*)Vt + ((n * 16 + lq) * 20 + g * 4) * 2);
      acc[n] = __builtin_amdgcn_mfma_f32_16x16x16bf16_1k(vf, pfv, acc[n], 0, 0, 0);
    }
  }

  const float inv = (l_run > 0.f) ? 1.f / l_run : 0.f;
  float* op = out + (((size_t)b * SLEN + qrow) * NH + h) * DH;
#pragma unroll
  for (int n = 0; n < 4; n++) {
    float4v o;
    o.x = acc[n][0] * inv; o.y = acc[n][1] * inv;
    o.z = acc[n][2] * inv; o.w = acc[n][3] * inv;
    *(float4v*)(op + n * 16 + g * 4) = o;
  }
}

extern "C" void kernel_launch(void* const* d_in, const int* in_sizes, int n_in,
                              void* d_out, int out_size, void* d_ws, size_t ws_size,
                              hipStream_t stream) {
  const float* q = (const float*)d_in[0];
  const float* k = (const float*)d_in[1];
  const float* v = (const float*)d_in[2];
  const void* mask = d_in[3];
  float* out = (float*)d_out;

  unsigned int* packed = (unsigned int*)((char*)d_ws + 256);   // 512 KB
  char* img = (char*)d_ws + (1 << 20);                         // 16 MB
  const size_t need = (size_t)(1 << 20) + (size_t)CONVBLK * TILEB;

  if (ws_size >= need) {
    prep_kernel<<<CONVBLK + PACKBLK, 256, 0, stream>>>(k, v, mask, img, packed, CONVBLK);
    sattn_fast12<<<NBATCH * NH * (SLEN / 128), 256, 0, stream>>>(q, packed, img, out);
  } else {
    prep_kernel<<<PACKBLK, 256, 0, stream>>>(k, v, mask, nullptr, packed, 0);
    sattn_fallback<<<NBATCH * NH * (SLEN / 64), 256, 0, stream>>>(q, k, v, packed, out);
  }
}

// Round 14
// 67.255 us; speedup vs baseline: 1.0806x; 1.0806x over previous
//
#include <hip/hip_runtime.h>
#include <hip/hip_bf16.h>
#include <math.h>

// SparseFlashAttention: B=2, S=2048, H=16, D=64, fp32 in/out, [S,S] bool mask.
#define SLEN 2048
#define NBATCH 2
#define NH 16
#define DH 64
#define WPR 64      // mask words per row
#define NROUND 32   // 64-key rounds
#define TILEB 16384 // bytes per 64-key fragment-image tile (K frags 0-7, V frags 8-15)
#define CONVBLK (NBATCH * NH * NROUND)          // 1024 conv blocks
#define PACKBLK (SLEN * WPR / 256)              // 512 pack blocks

typedef __attribute__((ext_vector_type(4))) short short4v;
typedef __attribute__((ext_vector_type(8))) short short8v;
typedef __attribute__((ext_vector_type(4))) float float4v;
typedef __attribute__((ext_vector_type(16))) float float16v;

__device__ __forceinline__ unsigned short f2bf(float f) {
  unsigned u = __float_as_uint(f);
  u += 0x7fffu + ((u >> 16) & 1u);
  return (unsigned short)(u >> 16);
}

__device__ __forceinline__ float fexp2(float x) {
#if __has_builtin(__builtin_amdgcn_exp2f)
  return __builtin_amdgcn_exp2f(x);
#else
  return __expf(x * 0.6931471805599453f);
#endif
}

// RNE pack via integer ops (prep/Q path)
__device__ __forceinline__ unsigned pack_bf2(float a, float b) {
  unsigned ua = __float_as_uint(a); ua += 0x7fffu + ((ua >> 16) & 1u);
  unsigned ub = __float_as_uint(b); ub += 0x7fffu + ((ub >> 16) & 1u);
  return __builtin_amdgcn_perm(ub, ua, 0x07060302u);
}

// HW packed f32->bf16x2: dst[15:0]=bf16(lo), dst[31:16]=bf16(hi). 1 VALU op.
__device__ __forceinline__ unsigned cvtpk(float lo, float hi) {
  unsigned r;
  asm("v_cvt_pk_bf16_f32 %0, %1, %2" : "=v"(r) : "v"(lo), "v"(hi));
  return r;
}

// bool-byte word (bytes in {0,1}) -> 4-bit nibble, bit j = byte j
__device__ __forceinline__ unsigned nib4(unsigned w) {
  return ((w * 0x01020408u) >> 24) & 0xFu;
}

// ---------------------------------------------------------------------------
// Fragment-image layout (verified R9): tile (bh, t) = 16 frags x 1024 B.
// Lane l of frag i reads bytes [i*1024 + l*16, +16) -- coalesced per wave.
//   K element (key r, dim d):  frag = (r>>5)*4 + (d>>4);
//     lane = ((d>>3)&1)*32 + (r&31); byte slot = (d&7)*2.
//   V element (key p, dim d):  frag = 8 + (d>>5)*4 + 2*(p>>5) + ((p>>4)&1);
//     lane = ((p>>2)&1)*32 + (d&31); slot = (4*((p>>3)&1) + (p&3))*2.
// ---------------------------------------------------------------------------
__global__ __launch_bounds__(256) void prep_kernel(
    const float* __restrict__ kk, const float* __restrict__ vv,
    const void* __restrict__ mask,
    char* __restrict__ img, unsigned* __restrict__ packed, int convblocks) {
  const int tid = threadIdx.x;
  if (blockIdx.x >= convblocks) {  // ---- mask pack with block-local self-detect
    const int w = (blockIdx.x - convblocks) * 256 + tid;
    const uint4* bp = (const uint4*)((const char*)mask + (size_t)w * 32);
    uint4 x = bp[0], y = bp[1];
    const unsigned orw = (x.x | x.y) | (x.z | x.w) | (y.x | y.y) | (y.z | y.w);
    __shared__ int s0, sm;
    if (tid == 0) { s0 = 0; sm = 0; }
    __syncthreads();
    const int lane0 = ((tid & 63) == 0);
    if (__any((orw & 0x000000ffu) != 0) && lane0) atomicOr(&s0, 1);
    if (__any((orw & 0xffffff00u) != 0) && lane0) atomicOr(&sm, 1);
    __syncthreads();
    unsigned bits;
    if (s0 && sm) {  // byte bools
      bits = nib4(x.x) | (nib4(x.y) << 4) | (nib4(x.z) << 8) | (nib4(x.w) << 12) |
             (nib4(y.x) << 16) | (nib4(y.y) << 20) | (nib4(y.z) << 24) | (nib4(y.w) << 28);
    } else {  // 32-bit words
      const unsigned* m = (const unsigned*)mask + (size_t)w * 32;
      bits = 0u;
#pragma unroll
      for (int j = 0; j < 32; j++) bits |= (m[j] ? 1u : 0u) << j;
    }
    packed[w] = bits;
    return;
  }
  // ---- conv (fragment images)
  const int bid = blockIdx.x;  // bh*32 + t
  const int t = bid & 31;
  const int bh = bid >> 5;
  const int b = bh >> 4, h = bh & 15;
  char* timg = img + (size_t)bid * TILEB;

  {  // K: thread -> (key r, 16-dim group dg); two 16B contiguous writes
    const int r = tid >> 2;
    const int dg = (tid & 3) << 4;
    const float* src = kk + (((size_t)(b * SLEN + t * 64 + r) * NH + h) * DH + dg);
    const int f = ((r >> 5) << 2) + (dg >> 4);
    char* base = timg + f * 1024 + (r & 31) * 16;  // hl=0 slot; hl=1 at +512
    float4v x0 = *(const float4v*)(src);
    float4v x1 = *(const float4v*)(src + 4);
    float4v x2 = *(const float4v*)(src + 8);
    float4v x3 = *(const float4v*)(src + 12);
    union { unsigned u[4]; short8v s8; } lo, hi;
    lo.u[0] = pack_bf2(x0.x, x0.y); lo.u[1] = pack_bf2(x0.z, x0.w);
    lo.u[2] = pack_bf2(x1.x, x1.y); lo.u[3] = pack_bf2(x1.z, x1.w);
    hi.u[0] = pack_bf2(x2.x, x2.y); hi.u[1] = pack_bf2(x2.z, x2.w);
    hi.u[2] = pack_bf2(x3.x, x3.y); hi.u[3] = pack_bf2(x3.z, x3.w);
    *(short8v*)(base) = lo.s8;
    *(short8v*)(base + 512) = hi.s8;
  }
  {  // V: thread -> (dim d, 16-key group kg); 2B transposed scatter
    const int d = tid >> 2;
    const int kg = (tid & 3) << 4;
    const float* src = vv + ((size_t)(b * SLEN + t * 64 + kg) * NH + h) * DH + d;
    const int fbase = 8 + ((d >> 5) << 2);
    const int l31d = d & 31;
#pragma unroll
    for (int i = 0; i < 16; i++) {
      const int p = kg + i;
      float x = src[(size_t)i * (NH * DH)];
      const int f = fbase + 2 * (p >> 5) + ((p >> 4) & 1);
      const int lane = ((p >> 2) & 1) * 32 + l31d;
      const int slot = 4 * ((p >> 3) & 1) + (p & 3);
      *(unsigned short*)(timg + f * 1024 + lane * 16 + slot * 2) = f2bf(x);
    }
  }
}

// ---------------------------------------------------------------------------
// Main kernel R14 = R9 (best passing: 63.7 us main) + base-pointer addressing
// only. No LDS, no barriers: 512 blocks x 4 independent waves, 32 rounds,
// fragments direct from L2 via coalesced dwordx4 (1 KB/instr), single-buffer
// rotate (K reloaded after QK, V after PV), verified bit-mask softmax,
// VALU lsum (R13's ones-lacc traded 32 VALU adds for +25% MFMA work -- net
// loss, reverted). 4 base pointers give immediate-offset loads (0..3072).
// ---------------------------------------------------------------------------
__global__ __launch_bounds__(256, 2) void sattn_fast13(
    const float* __restrict__ q, const unsigned* __restrict__ pmask,
    const char* __restrict__ img, float* __restrict__ out) {
  const int tid = threadIdx.x;
  const int xcd = blockIdx.x & 7;
  const int j = blockIdx.x >> 3;            // 0..63
  const int bh = xcd * 4 + (j >> 4);        // 4 bh per XCD -> images L2-resident
  const int chunk = j & 15;                 // 16 chunks of 128 queries
  const int b = bh >> 4;
  const int hd = bh & 15;
  const int wave = tid >> 6;
  const int lane = tid & 63;
  const int l31 = lane & 31;
  const int hl = lane >> 5;

  const int qrow = chunk * 128 + wave * 32 + l31;
  const int qw = qrow * WPR;

  // Q B-frags, pre-scaled by (1/sqrt(64))*log2(e); qf[ds] elem j = Q[q][16ds+8hl+j]
  const float SCL2 = 0.18033688011112042f;
  short8v qf[4];
  {
    const float* qp = q + (((size_t)b * SLEN + qrow) * NH + hd) * DH;
#pragma unroll
    for (int ds = 0; ds < 4; ds++) {
      float4v x0 = *(const float4v*)(qp + ds * 16 + hl * 8);
      float4v x1 = *(const float4v*)(qp + ds * 16 + hl * 8 + 4);
      union { unsigned u[4]; short8v s8; } cv;
      cv.u[0] = pack_bf2(x0.x * SCL2, x0.y * SCL2);
      cv.u[1] = pack_bf2(x0.z * SCL2, x0.w * SCL2);
      cv.u[2] = pack_bf2(x1.x * SCL2, x1.y * SCL2);
      cv.u[3] = pack_bf2(x1.z * SCL2, x1.w * SCL2);
      qf[ds] = cv.s8;
    }
  }

  // 4 fragment base pointers (imm offsets 0..3072 within each)
  const char* fb0 = img + (size_t)bh * (NROUND * TILEB) + lane * 16;
  const char* fb1 = fb0 + 4096;
  const char* fb2 = fb0 + 8192;
  const char* fb3 = fb0 + 12288;

  float16v acc0 = {}, acc1 = {};
  float lsum = 0.f;

  // prologue: round-0 fragments + mask
  short8v kf0 = *(const short8v*)(fb0 + 0);
  short8v kf1 = *(const short8v*)(fb0 + 1024);
  short8v kf2 = *(const short8v*)(fb0 + 2048);
  short8v kf3 = *(const short8v*)(fb0 + 3072);
  short8v kf4 = *(const short8v*)(fb1 + 0);
  short8v kf5 = *(const short8v*)(fb1 + 1024);
  short8v kf6 = *(const short8v*)(fb1 + 2048);
  short8v kf7 = *(const short8v*)(fb1 + 3072);
  short8v vf0 = *(const short8v*)(fb2 + 0);
  short8v vf1 = *(const short8v*)(fb2 + 1024);
  short8v vf2 = *(const short8v*)(fb2 + 2048);
  short8v vf3 = *(const short8v*)(fb2 + 3072);
  short8v vf4 = *(const short8v*)(fb3 + 0);
  short8v vf5 = *(const short8v*)(fb3 + 1024);
  short8v vf6 = *(const short8v*)(fb3 + 2048);
  short8v vf7 = *(const short8v*)(fb3 + 3072);
  uint2 m = *(const uint2*)&pmask[qw];

  for (int t = 0; t < NROUND; t++) {
    const unsigned m0 = m.x, m1 = m.y;
    const int tn = (t + 1 < NROUND) ? t + 1 : t;  // last-iter reload harmless

    // ---- QK^T: st0 = keys 0..31, st1 = keys 32..63 of this tile
    __builtin_amdgcn_s_setprio(1);
    float16v st0 = {}, st1 = {};
    st0 = __builtin_amdgcn_mfma_f32_32x32x16_bf16(kf0, qf[0], st0, 0, 0, 0);
    st1 = __builtin_amdgcn_mfma_f32_32x32x16_bf16(kf4, qf[0], st1, 0, 0, 0);
    st0 = __builtin_amdgcn_mfma_f32_32x32x16_bf16(kf1, qf[1], st0, 0, 0, 0);
    st1 = __builtin_amdgcn_mfma_f32_32x32x16_bf16(kf5, qf[1], st1, 0, 0, 0);
    st0 = __builtin_amdgcn_mfma_f32_32x32x16_bf16(kf2, qf[2], st0, 0, 0, 0);
    st1 = __builtin_amdgcn_mfma_f32_32x32x16_bf16(kf6, qf[2], st1, 0, 0, 0);
    st0 = __builtin_amdgcn_mfma_f32_32x32x16_bf16(kf3, qf[3], st0, 0, 0, 0);
    st1 = __builtin_amdgcn_mfma_f32_32x32x16_bf16(kf7, qf[3], st1, 0, 0, 0);
    __builtin_amdgcn_s_setprio(0);

    // ---- advance bases (clamped on last round) + reload K/mask for t+1
    const int adv = (tn != t) ? TILEB : 0;
    fb0 += adv; fb1 += adv; fb2 += adv; fb3 += adv;
    kf0 = *(const short8v*)(fb0 + 0);
    kf1 = *(const short8v*)(fb0 + 1024);
    kf2 = *(const short8v*)(fb0 + 2048);
    kf3 = *(const short8v*)(fb0 + 3072);
    kf4 = *(const short8v*)(fb1 + 0);
    kf5 = *(const short8v*)(fb1 + 1024);
    kf6 = *(const short8v*)(fb1 + 2048);
    kf7 = *(const short8v*)(fb1 + 3072);
    m = *(const uint2*)&pmask[qw + 2 * tn];

    // ---- softmax + mask + pack (verified bit-mask path)
    // reg r of st_h <-> key 32h + (r&3) + 8*(r>>2) + 4*hl
    float p0[16], p1[16];
#pragma unroll
    for (int u = 0; u < 4; u++) {
      const unsigned hw0 = m0 >> (8 * u + 4 * hl);
      const unsigned hw1 = m1 >> (8 * u + 4 * hl);
      {
        float a0 = fexp2(st0[4 * u + 0]); a0 = (hw0 & 1u) ? a0 : 0.f;
        float a1 = fexp2(st0[4 * u + 1]); a1 = (hw0 & 2u) ? a1 : 0.f;
        float a2 = fexp2(st0[4 * u + 2]); a2 = (hw0 & 4u) ? a2 : 0.f;
        float a3 = fexp2(st0[4 * u + 3]); a3 = (hw0 & 8u) ? a3 : 0.f;
        lsum += (a0 + a1) + (a2 + a3);
        p0[4 * u + 0] = a0; p0[4 * u + 1] = a1; p0[4 * u + 2] = a2; p0[4 * u + 3] = a3;
      }
      {
        float a0 = fexp2(st1[4 * u + 0]); a0 = (hw1 & 1u) ? a0 : 0.f;
        float a1 = fexp2(st1[4 * u + 1]); a1 = (hw1 & 2u) ? a1 : 0.f;
        float a2 = fexp2(st1[4 * u + 2]); a2 = (hw1 & 4u) ? a2 : 0.f;
        float a3 = fexp2(st1[4 * u + 3]); a3 = (hw1 & 8u) ? a3 : 0.f;
        lsum += (a0 + a1) + (a2 + a3);
        p1[4 * u + 0] = a0; p1[4 * u + 1] = a1; p1[4 * u + 2] = a2; p1[4 * u + 3] = a3;
      }
    }
    // pf[kc] = B-frag of key-group kc: slot j = C/D reg 8*(kc&1)+j of st[kc>>1]
    short8v pf0, pf1, pf2, pf3;
    {
      union { unsigned u[4]; short8v s8; } c0, c1, c2, c3;
#pragma unroll
      for (int jj = 0; jj < 4; jj++) {
        c0.u[jj] = cvtpk(p0[2 * jj], p0[2 * jj + 1]);
        c1.u[jj] = cvtpk(p0[8 + 2 * jj], p0[8 + 2 * jj + 1]);
        c2.u[jj] = cvtpk(p1[2 * jj], p1[2 * jj + 1]);
        c3.u[jj] = cvtpk(p1[8 + 2 * jj], p1[8 + 2 * jj + 1]);
      }
      pf0 = c0.s8; pf1 = c1.s8; pf2 = c2.s8; pf3 = c3.s8;
    }

    // ---- PV (V-frag kc for d-half n: vf[n*4+kc])
    __builtin_amdgcn_s_setprio(1);
    acc0 = __builtin_amdgcn_mfma_f32_32x32x16_bf16(vf0, pf0, acc0, 0, 0, 0);
    acc1 = __builtin_amdgcn_mfma_f32_32x32x16_bf16(vf4, pf0, acc1, 0, 0, 0);
    acc0 = __builtin_amdgcn_mfma_f32_32x32x16_bf16(vf1, pf1, acc0, 0, 0, 0);
    acc1 = __builtin_amdgcn_mfma_f32_32x32x16_bf16(vf5, pf1, acc1, 0, 0, 0);
    acc0 = __builtin_amdgcn_mfma_f32_32x32x16_bf16(vf2, pf2, acc0, 0, 0, 0);
    acc1 = __builtin_amdgcn_mfma_f32_32x32x16_bf16(vf6, pf2, acc1, 0, 0, 0);
    acc0 = __builtin_amdgcn_mfma_f32_32x32x16_bf16(vf3, pf3, acc0, 0, 0, 0);
    acc1 = __builtin_amdgcn_mfma_f32_32x32x16_bf16(vf7, pf3, acc1, 0, 0, 0);
    __builtin_amdgcn_s_setprio(0);

    // ---- reload V for t+1
    vf0 = *(const short8v*)(fb2 + 0);
    vf1 = *(const short8v*)(fb2 + 1024);
    vf2 = *(const short8v*)(fb2 + 2048);
    vf3 = *(const short8v*)(fb2 + 3072);
    vf4 = *(const short8v*)(fb3 + 0);
    vf5 = *(const short8v*)(fb3 + 1024);
    vf6 = *(const short8v*)(fb3 + 2048);
    vf7 = *(const short8v*)(fb3 + 3072);
  }

  // q = l31 row total = this lane's partial + the other hl's partial
  lsum += __shfl_xor(lsum, 32);
  const float inv = (lsum > 0.f) ? 1.f / lsum : 0.f;
  float* op = out + (((size_t)b * SLEN + qrow) * NH + hd) * DH;
#pragma unroll
  for (int u = 0; u < 4; u++) {
    float4v o0, o1;
    o0.x = acc0[4 * u + 0] * inv; o0.y = acc0[4 * u + 1] * inv;
    o0.z = acc0[4 * u + 2] * inv; o0.w = acc0[4 * u + 3] * inv;
    o1.x = acc1[4 * u + 0] * inv; o1.y = acc1[4 * u + 1] * inv;
    o1.z = acc1[4 * u + 2] * inv; o1.w = acc1[4 * u + 3] * inv;
    *(float4v*)(op + 8 * u + 4 * hl) = o0;
    *(float4v*)(op + 32 + 8 * u + 4 * hl) = o1;
  }
}

// ---------------------------------------------------------------------------
// Fallback (R1 kernel, verified): used only if ws_size can't hold the images.
// ---------------------------------------------------------------------------
__global__ __launch_bounds__(256) void sattn_fallback(
    const float* __restrict__ q, const float* __restrict__ kk,
    const float* __restrict__ vv, const unsigned int* __restrict__ pmask,
    float* __restrict__ out) {
  __shared__ __align__(16) unsigned short Kt[16 * 64];
  __shared__ __align__(16) unsigned short Vt[64 * 20];

  const int tid = threadIdx.x;
  const int chunk = blockIdx.x & 31;
  const int bh = blockIdx.x >> 5;
  const int b = bh >> 4;
  const int h = bh & 15;
  const int wave = tid >> 6;
  const int lane = tid & 63;
  const int lq = lane & 15;
  const int g = lane >> 4;

  const int qrow = chunk * 64 + wave * 16 + lq;

  short4v qf[4];
  {
    const float* qp = q + (((size_t)b * SLEN + qrow) * NH + h) * DH;
#pragma unroll
    for (int ks = 0; ks < 4; ks++) {
      float4v x = *(const float4v*)(qp + ks * 16 + g * 4);
      short4v s;
      s.x = (short)f2bf(x.x); s.y = (short)f2bf(x.y);
      s.z = (short)f2bf(x.z); s.w = (short)f2bf(x.w);
      qf[ks] = s;
    }
  }

  const int srow = tid >> 4;
  const int scol = (tid & 15) * 4;
  const size_t kvbase = (size_t)b * SLEN * (NH * DH) + (size_t)h * DH;

  float4v acc[4] = {};
  float m_run = -INFINITY;
  float l_run = 0.f;

  for (int t = 0; t < SLEN / 16; t++) {
    const int kbase = t * 16;
    __syncthreads();
    {
      const size_t rowoff = kvbase + (size_t)(kbase + srow) * (NH * DH) + scol;
      float4v x = *(const float4v*)(kk + rowoff);
      short4v s;
      s.x = (short)f2bf(x.x); s.y = (short)f2bf(x.y);
      s.z = (short)f2bf(x.z); s.w = (short)f2bf(x.w);
      const int off = (scol * 2) ^ ((srow & 7) << 4);
      *(short4v*)((char*)Kt + srow * 128 + off) = s;

      float4v y = *(const float4v*)(vv + rowoff);
      Vt[(scol + 0) * 20 + srow] = f2bf(y.x);
      Vt[(scol + 1) * 20 + srow] = f2bf(y.y);
      Vt[(scol + 2) * 20 + srow] = f2bf(y.z);
      Vt[(scol + 3) * 20 + srow] = f2bf(y.w);
    }
    __syncthreads();

    float4v stv = {0.f, 0.f, 0.f, 0.f};
#pragma unroll
    for (int ks = 0; ks < 4; ks++) {
      const int off = ((ks * 16 + g * 4) * 2) ^ ((lq & 7) << 4);
      short4v kf = *(const short4v*)((const char*)Kt + lq * 128 + off);
      stv = __builtin_amdgcn_mfma_f32_16x16x16bf16_1k(kf, qf[ks], stv, 0, 0, 0);
    }

    const unsigned int mw = pmask[qrow * WPR + (kbase >> 5)];
    const int shift = (kbase & 16) + g * 4;
    float sc[4];
    float tmax = -INFINITY;
#pragma unroll
    for (int r = 0; r < 4; r++) {
      bool a = (mw >> (shift + r)) & 1u;
      sc[r] = a ? stv[r] * 0.125f : -INFINITY;
      tmax = fmaxf(tmax, sc[r]);
    }
    tmax = fmaxf(tmax, __shfl_xor(tmax, 16));
    tmax = fmaxf(tmax, __shfl_xor(tmax, 32));
    const float mnew = fmaxf(m_run, tmax);
    const float muse = (mnew > -1e37f) ? mnew : 0.f;
    const float alpha = __expf(m_run - muse);
    float p[4], tsum = 0.f;
#pragma unroll
    for (int r = 0; r < 4; r++) {
      p[r] = __expf(sc[r] - muse);
      tsum += p[r];
    }
    tsum += __shfl_xor(tsum, 16);
    tsum += __shfl_xor(tsum, 32);
    l_run = l_run * alpha + tsum;
    m_run = mnew;

    short4v pfv;
    pfv.x = (short)f2bf(p[0]); pfv.y = (short)f2bf(p[1]);
    pfv.z = (short)f2bf(p[2]); pfv.w = (short)f2bf(p[3]);

#pragma unroll
    for (int n = 0; n < 4; n++) {
      acc[n][0] *= alpha; acc[n][1] *= alpha;
      acc[n][2] *= alpha; acc[n][3] *= alpha;
      short4v vf = *(const short4v*)((const char*)Vt + ((n * 16 + lq) * 20 + g * 4) * 2);
      acc[n] = __builtin_amdgcn_mfma_f32_16x16x16bf16_1k(vf, pfv, acc[n], 0, 0, 0);
    }
  }

  const float inv = (l_run > 0.f) ? 1.f / l_run : 0.f;
  float* op = out + (((size_t)b * SLEN + qrow) * NH + h) * DH;
#pragma unroll
  for (int n = 0; n < 4; n++) {
    float4v o;
    o.x = acc[n][0] * inv; o.y = acc[n][1] * inv;
    o.z = acc[n][2] * inv; o.w = acc[n][3] * inv;
    *(float4v*)(op + n * 16 + g * 4) = o;
  }
}

extern "C" void kernel_launch(void* const* d_in, const int* in_sizes, int n_in,
                              void* d_out, int out_size, void* d_ws, size_t ws_size,
                              hipStream_t stream) {
  const float* q = (const float*)d_in[0];
  const float* k = (const float*)d_in[1];
  const float* v = (const float*)d_in[2];
  const void* mask = d_in[3];
  float* out = (float*)d_out;

  unsigned int* packed = (unsigned int*)((char*)d_ws + 256);   // 512 KB
  char* img = (char*)d_ws + (1 << 20);                         // 16 MB
  const size_t need = (size_t)(1 << 20) + (size_t)CONVBLK * TILEB;

  if (ws_size >= need) {
    prep_kernel<<<CONVBLK + PACKBLK, 256, 0, stream>>>(k, v, mask, img, packed, CONVBLK);
    sattn_fast13<<<NBATCH * NH * (SLEN / 128), 256, 0, stream>>>(q, packed, img, out);
  } else {
    prep_kernel<<<PACKBLK, 256, 0, stream>>>(k, v, mask, nullptr, packed, 0);
    sattn_fallback<<<NBATCH * NH * (SLEN / 64), 256, 0, stream>>>(q, k, v, packed, out);
  }
}

// Round 15
// 66.700 us; speedup vs baseline: 1.0896x; 1.0083x over previous
//
#include <hip/hip_runtime.h>
#include <hip/hip_bf16.h>
#include <math.h>

// SparseFlashAttention: B=2, S=2048, H=16, D=64, fp32 in/out, [S,S] bool mask.
#define SLEN 2048
#define NBATCH 2
#define NH 16
#define DH 64
#define WPR 64      // mask words per row
#define NROUND 32   // 64-key rounds
#define TILEB 16384 // bytes per 64-key fragment-image tile (K frags 0-7, V frags 8-15)
#define CONVBLK (NBATCH * NH * NROUND)          // 1024 conv blocks
#define PACKBLK (SLEN * WPR / 256)              // 512 pack blocks

typedef __attribute__((ext_vector_type(4))) short short4v;
typedef __attribute__((ext_vector_type(8))) short short8v;
typedef __attribute__((ext_vector_type(4))) float float4v;
typedef __attribute__((ext_vector_type(16))) float float16v;

__device__ __forceinline__ unsigned short f2bf(float f) {
  unsigned u = __float_as_uint(f);
  u += 0x7fffu + ((u >> 16) & 1u);
  return (unsigned short)(u >> 16);
}

__device__ __forceinline__ float fexp2(float x) {
#if __has_builtin(__builtin_amdgcn_exp2f)
  return __builtin_amdgcn_exp2f(x);
#else
  return __expf(x * 0.6931471805599453f);
#endif
}

// RNE pack via integer ops (prep/Q path)
__device__ __forceinline__ unsigned pack_bf2(float a, float b) {
  unsigned ua = __float_as_uint(a); ua += 0x7fffu + ((ua >> 16) & 1u);
  unsigned ub = __float_as_uint(b); ub += 0x7fffu + ((ub >> 16) & 1u);
  return __builtin_amdgcn_perm(ub, ua, 0x07060302u);
}

// HW packed f32->bf16x2: dst[15:0]=bf16(lo), dst[31:16]=bf16(hi). 1 VALU op.
__device__ __forceinline__ unsigned cvtpk(float lo, float hi) {
  unsigned r;
  asm("v_cvt_pk_bf16_f32 %0, %1, %2" : "=v"(r) : "v"(lo), "v"(hi));
  return r;
}

// bool-byte word (bytes in {0,1}) -> 4-bit nibble, bit j = byte j
__device__ __forceinline__ unsigned nib4(unsigned w) {
  return ((w * 0x01020408u) >> 24) & 0xFu;
}

// ---------------------------------------------------------------------------
// Fragment-image layout (verified R9): tile (bh, t) = 16 frags x 1024 B.
// Lane l of frag i reads bytes [i*1024 + l*16, +16) -- coalesced per wave.
//   K element (key r, dim d):  frag = (r>>5)*4 + (d>>4);
//     lane = ((d>>3)&1)*32 + (r&31); byte slot = (d&7)*2.
//   V element (key p, dim d):  frag = 8 + (d>>5)*4 + 2*(p>>5) + ((p>>4)&1);
//     lane = ((p>>2)&1)*32 + (d&31); slot = (4*((p>>3)&1) + (p&3))*2.
// R15: V path now stages through LDS so GLOBAL writes are coalesced 16B
// (was: 16 scalar 2B scatter-stores/thread = ~8x cacheline write-amp).
// Cell inversion (given fp=f-8, lane16, slot):
//   d = ((fp>>2)&1)*32 + (lane16&31)
//   p = 32*((fp>>1)&1) + 16*(fp&1) + 8*(slot>>2) + 4*(lane16>>5) + (slot&3)
// Hand-checked: (p=17,d=0)->frag9/lane0/slot1; (p=44,d=37)->frag14/lane37/slot4.
// ---------------------------------------------------------------------------
__global__ __launch_bounds__(256) void prep_kernel(
    const float* __restrict__ kk, const float* __restrict__ vv,
    const void* __restrict__ mask,
    char* __restrict__ img, unsigned* __restrict__ packed, int convblocks) {
  const int tid = threadIdx.x;
  if (blockIdx.x >= convblocks) {  // ---- mask pack with block-local self-detect
    const int w = (blockIdx.x - convblocks) * 256 + tid;
    const uint4* bp = (const uint4*)((const char*)mask + (size_t)w * 32);
    uint4 x = bp[0], y = bp[1];
    const unsigned orw = (x.x | x.y) | (x.z | x.w) | (y.x | y.y) | (y.z | y.w);
    __shared__ int s0, sm;
    if (tid == 0) { s0 = 0; sm = 0; }
    __syncthreads();
    const int lane0 = ((tid & 63) == 0);
    if (__any((orw & 0x000000ffu) != 0) && lane0) atomicOr(&s0, 1);
    if (__any((orw & 0xffffff00u) != 0) && lane0) atomicOr(&sm, 1);
    __syncthreads();
    unsigned bits;
    if (s0 && sm) {  // byte bools
      bits = nib4(x.x) | (nib4(x.y) << 4) | (nib4(x.z) << 8) | (nib4(x.w) << 12) |
             (nib4(y.x) << 16) | (nib4(y.y) << 20) | (nib4(y.z) << 24) | (nib4(y.w) << 28);
    } else {  // 32-bit words
      const unsigned* m = (const unsigned*)mask + (size_t)w * 32;
      bits = 0u;
#pragma unroll
      for (int j = 0; j < 32; j++) bits |= (m[j] ? 1u : 0u) << j;
    }
    packed[w] = bits;
    return;
  }
  // ---- conv (fragment images)
  const int bid = blockIdx.x;  // bh*32 + t
  const int t = bid & 31;
  const int bh = bid >> 5;
  const int b = bh >> 4, h = bh & 15;
  char* timg = img + (size_t)bid * TILEB;

  {  // K: thread -> (key r, 16-dim group dg); two 16B contiguous writes
    const int r = tid >> 2;
    const int dg = (tid & 3) << 4;
    const float* src = kk + (((size_t)(b * SLEN + t * 64 + r) * NH + h) * DH + dg);
    const int f = ((r >> 5) << 2) + (dg >> 4);
    char* base = timg + f * 1024 + (r & 31) * 16;  // hl=0 slot; hl=1 at +512
    float4v x0 = *(const float4v*)(src);
    float4v x1 = *(const float4v*)(src + 4);
    float4v x2 = *(const float4v*)(src + 8);
    float4v x3 = *(const float4v*)(src + 12);
    union { unsigned u[4]; short8v s8; } lo, hi;
    lo.u[0] = pack_bf2(x0.x, x0.y); lo.u[1] = pack_bf2(x0.z, x0.w);
    lo.u[2] = pack_bf2(x1.x, x1.y); lo.u[3] = pack_bf2(x1.z, x1.w);
    hi.u[0] = pack_bf2(x2.x, x2.y); hi.u[1] = pack_bf2(x2.z, x2.w);
    hi.u[2] = pack_bf2(x3.x, x3.y); hi.u[3] = pack_bf2(x3.z, x3.w);
    *(short8v*)(base) = lo.s8;
    *(short8v*)(base + 512) = hi.s8;
  }
  {  // V: coalesced f32 reads -> bf16 LDS [key][d] (stride 68) -> coalesced
    // 16B fragment-cell stores.
    __shared__ unsigned short vlds[64 * 68];
    const int key = tid >> 2;
    const int dg = (tid & 3) << 4;
    const float* src = vv + (((size_t)(b * SLEN + t * 64 + key) * NH + h) * DH + dg);
    unsigned short* lp = vlds + key * 68 + dg;
#pragma unroll
    for (int i = 0; i < 4; i++) {
      float4v x = *(const float4v*)(src + i * 4);
      union { unsigned u[2]; short4v s4; } cv;
      cv.u[0] = pack_bf2(x.x, x.y);
      cv.u[1] = pack_bf2(x.z, x.w);
      *(short4v*)(lp + i * 4) = cv.s4;
    }
    __syncthreads();
#pragma unroll
    for (int c = 0; c < 2; c++) {
      const int cell = c * 256 + tid;    // consecutive tid -> consecutive 16B
      const int fp = cell >> 6;          // 0..7 (frag = 8 + fp)
      const int lane16 = cell & 63;
      const int d = ((fp >> 2) & 1) * 32 + (lane16 & 31);
      const int pbase = 32 * ((fp >> 1) & 1) + 16 * (fp & 1) + 4 * (lane16 >> 5);
      union { unsigned short s[8]; short8v v8; } w;
#pragma unroll
      for (int slot = 0; slot < 8; slot++) {
        const int p = pbase + 8 * (slot >> 2) + (slot & 3);
        w.s[slot] = vlds[p * 68 + d];
      }
      *(short8v*)(timg + (8 + fp) * 1024 + lane16 * 16) = w.v8;
    }
  }
}

// ---------------------------------------------------------------------------
// Main kernel (R14, verified best: 59.8-61.8 us): no LDS, no barriers,
// 512 blocks x 4 independent waves, 32 rounds, fragments direct from L2 via
// coalesced dwordx4, single-buffer rotate, bit-mask softmax, VALU lsum,
// 4 base pointers with immediate offsets. UNCHANGED this round.
// ---------------------------------------------------------------------------
__global__ __launch_bounds__(256, 2) void sattn_fast13(
    const float* __restrict__ q, const unsigned* __restrict__ pmask,
    const char* __restrict__ img, float* __restrict__ out) {
  const int tid = threadIdx.x;
  const int xcd = blockIdx.x & 7;
  const int j = blockIdx.x >> 3;            // 0..63
  const int bh = xcd * 4 + (j >> 4);        // 4 bh per XCD -> images L2-resident
  const int chunk = j & 15;                 // 16 chunks of 128 queries
  const int b = bh >> 4;
  const int hd = bh & 15;
  const int wave = tid >> 6;
  const int lane = tid & 63;
  const int l31 = lane & 31;
  const int hl = lane >> 5;

  const int qrow = chunk * 128 + wave * 32 + l31;
  const int qw = qrow * WPR;

  // Q B-frags, pre-scaled by (1/sqrt(64))*log2(e); qf[ds] elem j = Q[q][16ds+8hl+j]
  const float SCL2 = 0.18033688011112042f;
  short8v qf[4];
  {
    const float* qp = q + (((size_t)b * SLEN + qrow) * NH + hd) * DH;
#pragma unroll
    for (int ds = 0; ds < 4; ds++) {
      float4v x0 = *(const float4v*)(qp + ds * 16 + hl * 8);
      float4v x1 = *(const float4v*)(qp + ds * 16 + hl * 8 + 4);
      union { unsigned u[4]; short8v s8; } cv;
      cv.u[0] = pack_bf2(x0.x * SCL2, x0.y * SCL2);
      cv.u[1] = pack_bf2(x0.z * SCL2, x0.w * SCL2);
      cv.u[2] = pack_bf2(x1.x * SCL2, x1.y * SCL2);
      cv.u[3] = pack_bf2(x1.z * SCL2, x1.w * SCL2);
      qf[ds] = cv.s8;
    }
  }

  // 4 fragment base pointers (imm offsets 0..3072 within each)
  const char* fb0 = img + (size_t)bh * (NROUND * TILEB) + lane * 16;
  const char* fb1 = fb0 + 4096;
  const char* fb2 = fb0 + 8192;
  const char* fb3 = fb0 + 12288;

  float16v acc0 = {}, acc1 = {};
  float lsum = 0.f;

  // prologue: round-0 fragments + mask
  short8v kf0 = *(const short8v*)(fb0 + 0);
  short8v kf1 = *(const short8v*)(fb0 + 1024);
  short8v kf2 = *(const short8v*)(fb0 + 2048);
  short8v kf3 = *(const short8v*)(fb0 + 3072);
  short8v kf4 = *(const short8v*)(fb1 + 0);
  short8v kf5 = *(const short8v*)(fb1 + 1024);
  short8v kf6 = *(const short8v*)(fb1 + 2048);
  short8v kf7 = *(const short8v*)(fb1 + 3072);
  short8v vf0 = *(const short8v*)(fb2 + 0);
  short8v vf1 = *(const short8v*)(fb2 + 1024);
  short8v vf2 = *(const short8v*)(fb2 + 2048);
  short8v vf3 = *(const short8v*)(fb2 + 3072);
  short8v vf4 = *(const short8v*)(fb3 + 0);
  short8v vf5 = *(const short8v*)(fb3 + 1024);
  short8v vf6 = *(const short8v*)(fb3 + 2048);
  short8v vf7 = *(const short8v*)(fb3 + 3072);
  uint2 m = *(const uint2*)&pmask[qw];

  for (int t = 0; t < NROUND; t++) {
    const unsigned m0 = m.x, m1 = m.y;
    const int tn = (t + 1 < NROUND) ? t + 1 : t;  // last-iter reload harmless

    // ---- QK^T: st0 = keys 0..31, st1 = keys 32..63 of this tile
    __builtin_amdgcn_s_setprio(1);
    float16v st0 = {}, st1 = {};
    st0 = __builtin_amdgcn_mfma_f32_32x32x16_bf16(kf0, qf[0], st0, 0, 0, 0);
    st1 = __builtin_amdgcn_mfma_f32_32x32x16_bf16(kf4, qf[0], st1, 0, 0, 0);
    st0 = __builtin_amdgcn_mfma_f32_32x32x16_bf16(kf1, qf[1], st0, 0, 0, 0);
    st1 = __builtin_amdgcn_mfma_f32_32x32x16_bf16(kf5, qf[1], st1, 0, 0, 0);
    st0 = __builtin_amdgcn_mfma_f32_32x32x16_bf16(kf2, qf[2], st0, 0, 0, 0);
    st1 = __builtin_amdgcn_mfma_f32_32x32x16_bf16(kf6, qf[2], st1, 0, 0, 0);
    st0 = __builtin_amdgcn_mfma_f32_32x32x16_bf16(kf3, qf[3], st0, 0, 0, 0);
    st1 = __builtin_amdgcn_mfma_f32_32x32x16_bf16(kf7, qf[3], st1, 0, 0, 0);
    __builtin_amdgcn_s_setprio(0);

    // ---- advance bases (clamped on last round) + reload K/mask for t+1
    const int adv = (tn != t) ? TILEB : 0;
    fb0 += adv; fb1 += adv; fb2 += adv; fb3 += adv;
    kf0 = *(const short8v*)(fb0 + 0);
    kf1 = *(const short8v*)(fb0 + 1024);
    kf2 = *(const short8v*)(fb0 + 2048);
    kf3 = *(const short8v*)(fb0 + 3072);
    kf4 = *(const short8v*)(fb1 + 0);
    kf5 = *(const short8v*)(fb1 + 1024);
    kf6 = *(const short8v*)(fb1 + 2048);
    kf7 = *(const short8v*)(fb1 + 3072);
    m = *(const uint2*)&pmask[qw + 2 * tn];

    // ---- softmax + mask + pack (verified bit-mask path)
    // reg r of st_h <-> key 32h + (r&3) + 8*(r>>2) + 4*hl
    float p0[16], p1[16];
#pragma unroll
    for (int u = 0; u < 4; u++) {
      const unsigned hw0 = m0 >> (8 * u + 4 * hl);
      const unsigned hw1 = m1 >> (8 * u + 4 * hl);
      {
        float a0 = fexp2(st0[4 * u + 0]); a0 = (hw0 & 1u) ? a0 : 0.f;
        float a1 = fexp2(st0[4 * u + 1]); a1 = (hw0 & 2u) ? a1 : 0.f;
        float a2 = fexp2(st0[4 * u + 2]); a2 = (hw0 & 4u) ? a2 : 0.f;
        float a3 = fexp2(st0[4 * u + 3]); a3 = (hw0 & 8u) ? a3 : 0.f;
        lsum += (a0 + a1) + (a2 + a3);
        p0[4 * u + 0] = a0; p0[4 * u + 1] = a1; p0[4 * u + 2] = a2; p0[4 * u + 3] = a3;
      }
      {
        float a0 = fexp2(st1[4 * u + 0]); a0 = (hw1 & 1u) ? a0 : 0.f;
        float a1 = fexp2(st1[4 * u + 1]); a1 = (hw1 & 2u) ? a1 : 0.f;
        float a2 = fexp2(st1[4 * u + 2]); a2 = (hw1 & 4u) ? a2 : 0.f;
        float a3 = fexp2(st1[4 * u + 3]); a3 = (hw1 & 8u) ? a3 : 0.f;
        lsum += (a0 + a1) + (a2 + a3);
        p1[4 * u + 0] = a0; p1[4 * u + 1] = a1; p1[4 * u + 2] = a2; p1[4 * u + 3] = a3;
      }
    }
    // pf[kc] = B-frag of key-group kc: slot j = C/D reg 8*(kc&1)+j of st[kc>>1]
    short8v pf0, pf1, pf2, pf3;
    {
      union { unsigned u[4]; short8v s8; } c0, c1, c2, c3;
#pragma unroll
      for (int jj = 0; jj < 4; jj++) {
        c0.u[jj] = cvtpk(p0[2 * jj], p0[2 * jj + 1]);
        c1.u[jj] = cvtpk(p0[8 + 2 * jj], p0[8 + 2 * jj + 1]);
        c2.u[jj] = cvtpk(p1[2 * jj], p1[2 * jj + 1]);
        c3.u[jj] = cvtpk(p1[8 + 2 * jj], p1[8 + 2 * jj + 1]);
      }
      pf0 = c0.s8; pf1 = c1.s8; pf2 = c2.s8; pf3 = c3.s8;
    }

    // ---- PV (V-frag kc for d-half n: vf[n*4+kc])
    __builtin_amdgcn_s_setprio(1);
    acc0 = __builtin_amdgcn_mfma_f32_32x32x16_bf16(vf0, pf0, acc0, 0, 0, 0);
    acc1 = __builtin_amdgcn_mfma_f32_32x32x16_bf16(vf4, pf0, acc1, 0, 0, 0);
    acc0 = __builtin_amdgcn_mfma_f32_32x32x16_bf16(vf1, pf1, acc0, 0, 0, 0);
    acc1 = __builtin_amdgcn_mfma_f32_32x32x16_bf16(vf5, pf1, acc1, 0, 0, 0);
    acc0 = __builtin_amdgcn_mfma_f32_32x32x16_bf16(vf2, pf2, acc0, 0, 0, 0);
    acc1 = __builtin_amdgcn_mfma_f32_32x32x16_bf16(vf6, pf2, acc1, 0, 0, 0);
    acc0 = __builtin_amdgcn_mfma_f32_32x32x16_bf16(vf3, pf3, acc0, 0, 0, 0);
    acc1 = __builtin_amdgcn_mfma_f32_32x32x16_bf16(vf7, pf3, acc1, 0, 0, 0);
    __builtin_amdgcn_s_setprio(0);

    // ---- reload V for t+1
    vf0 = *(const short8v*)(fb2 + 0);
    vf1 = *(const short8v*)(fb2 + 1024);
    vf2 = *(const short8v*)(fb2 + 2048);
    vf3 = *(const short8v*)(fb2 + 3072);
    vf4 = *(const short8v*)(fb3 + 0);
    vf5 = *(const short8v*)(fb3 + 1024);
    vf6 = *(const short8v*)(fb3 + 2048);
    vf7 = *(const short8v*)(fb3 + 3072);
  }

  // q = l31 row total = this lane's partial + the other hl's partial
  lsum += __shfl_xor(lsum, 32);
  const float inv = (lsum > 0.f) ? 1.f / lsum : 0.f;
  float* op = out + (((size_t)b * SLEN + qrow) * NH + hd) * DH;
#pragma unroll
  for (int u = 0; u < 4; u++) {
    float4v o0, o1;
    o0.x = acc0[4 * u + 0] * inv; o0.y = acc0[4 * u + 1] * inv;
    o0.z = acc0[4 * u + 2] * inv; o0.w = acc0[4 * u + 3] * inv;
    o1.x = acc1[4 * u + 0] * inv; o1.y = acc1[4 * u + 1] * inv;
    o1.z = acc1[4 * u + 2] * inv; o1.w = acc1[4 * u + 3] * inv;
    *(float4v*)(op + 8 * u + 4 * hl) = o0;
    *(float4v*)(op + 32 + 8 * u + 4 * hl) = o1;
  }
}

// ---------------------------------------------------------------------------
// Fallback (R1 kernel, verified): used only if ws_size can't hold the images.
// ---------------------------------------------------------------------------
__global__ __launch_bounds__(256) void sattn_fallback(
    const float* __restrict__ q, const float* __restrict__ kk,
    const float* __restrict__ vv, const unsigned int* __restrict__ pmask,
    float* __restrict__ out) {
  __shared__ __align__(16) unsigned short Kt[16 * 64];
  __shared__ __align__(16) unsigned short Vt[64 * 20];

  const int tid = threadIdx.x;
  const int chunk = blockIdx.x & 31;
  const int bh = blockIdx.x >> 5;
  const int b = bh >> 4;
  const int h = bh & 15;
  const int wave = tid >> 6;
  const int lane = tid & 63;
  const int lq = lane & 15;
  const int g = lane >> 4;

  const int qrow = chunk * 64 + wave * 16 + lq;

  short4v qf[4];
  {
    const float* qp = q + (((size_t)b * SLEN + qrow) * NH + h) * DH;
#pragma unroll
    for (int ks = 0; ks < 4; ks++) {
      float4v x = *(const float4v*)(qp + ks * 16 + g * 4);
      short4v s;
      s.x = (short)f2bf(x.x); s.y = (short)f2bf(x.y);
      s.z = (short)f2bf(x.z); s.w = (short)f2bf(x.w);
      qf[ks] = s;
    }
  }

  const int srow = tid >> 4;
  const int scol = (tid & 15) * 4;
  const size_t kvbase = (size_t)b * SLEN * (NH * DH) + (size_t)h * DH;

  float4v acc[4] = {};
  float m_run = -INFINITY;
  float l_run = 0.f;

  for (int t = 0; t < SLEN / 16; t++) {
    const int kbase = t * 16;
    __syncthreads();
    {
      const size_t rowoff = kvbase + (size_t)(kbase + srow) * (NH * DH) + scol;
      float4v x = *(const float4v*)(kk + rowoff);
      short4v s;
      s.x = (short)f2bf(x.x); s.y = (short)f2bf(x.y);
      s.z = (short)f2bf(x.z); s.w = (short)f2bf(x.w);
      const int off = (scol * 2) ^ ((srow & 7) << 4);
      *(short4v*)((char*)Kt + srow * 128 + off) = s;

      float4v y = *(const float4v*)(vv + rowoff);
      Vt[(scol + 0) * 20 + srow] = f2bf(y.x);
      Vt[(scol + 1) * 20 + srow] = f2bf(y.y);
      Vt[(scol + 2) * 20 + srow] = f2bf(y.z);
      Vt[(scol + 3) * 20 + srow] = f2bf(y.w);
    }
    __syncthreads();

    float4v stv = {0.f, 0.f, 0.f, 0.f};
#pragma unroll
    for (int ks = 0; ks < 4; ks++) {
      const int off = ((ks * 16 + g * 4) * 2) ^ ((lq & 7) << 4);
      short4v kf = *(const short4v*)((const char*)Kt + lq * 128 + off);
      stv = __builtin_amdgcn_mfma_f32_16x16x16bf16_1k(kf, qf[ks], stv, 0, 0, 0);
    }

    const unsigned int mw = pmask[qrow * WPR + (kbase >> 5)];
    const int shift = (kbase & 16) + g * 4;
    float sc[4];
    float tmax = -INFINITY;
#pragma unroll
    for (int r = 0; r < 4; r++) {
      bool a = (mw >> (shift + r)) & 1u;
      sc[r] = a ? stv[r] * 0.125f : -INFINITY;
      tmax = fmaxf(tmax, sc[r]);
    }
    tmax = fmaxf(tmax, __shfl_xor(tmax, 16));
    tmax = fmaxf(tmax, __shfl_xor(tmax, 32));
    const float mnew = fmaxf(m_run, tmax);
    const float muse = (mnew > -1e37f) ? mnew : 0.f;
    const float alpha = __expf(m_run - muse);
    float p[4], tsum = 0.f;
#pragma unroll
    for (int r = 0; r < 4; r++) {
      p[r] = __expf(sc[r] - muse);
      tsum += p[r];
    }
    tsum += __shfl_xor(tsum, 16);
    tsum += __shfl_xor(tsum, 32);
    l_run = l_run * alpha + tsum;
    m_run = mnew;

    short4v pfv;
    pfv.x = (short)f2bf(p[0]); pfv.y = (short)f2bf(p[1]);
    pfv.z = (short)f2bf(p[2]); pfv.w = (short)f2bf(p[3]);

#pragma unroll
    for (int n = 0; n < 4; n++) {
      acc[n][0] *= alpha; acc[n][1] *= alpha;
      acc[n][2] *= alpha; acc[n][3] *= alpha;
      short4v vf = *(const short4v*)((const char*)Vt + ((n * 16 + lq) * 20 + g * 4) * 2);
      acc[n] = __builtin_amdgcn_mfma_f32_16x16x16bf16_1k(vf, pfv, acc[n], 0, 0, 0);
    }
  }

  const float inv = (l_run > 0.f) ? 1.f / l_run : 0.f;
  float* op = out + (((size_t)b * SLEN + qrow) * NH + h) * DH;
#pragma unroll
  for (int n = 0; n < 4; n++) {
    float4v o;
    o.x = acc[n][0] * inv; o.y = acc[n][1] * inv;
    o.z = acc[n][2] * inv; o.w = acc[n][3] * inv;
    *(float4v*)(op + n * 16 + g * 4) = o;
  }
}

extern "C" void kernel_launch(void* const* d_in, const int* in_sizes, int n_in,
                              void* d_out, int out_size, void* d_ws, size_t ws_size,
                              hipStream_t stream) {
  const float* q = (const float*)d_in[0];
  const float* k = (const float*)d_in[1];
  const float* v = (const float*)d_in[2];
  const void* mask = d_in[3];
  float* out = (float*)d_out;

  unsigned int* packed = (unsigned int*)((char*)d_ws + 256);   // 512 KB
  char* img = (char*)d_ws + (1 << 20);                         // 16 MB
  const size_t need = (size_t)(1 << 20) + (size_t)CONVBLK * TILEB;

  if (ws_size >= need) {
    prep_kernel<<<CONVBLK + PACKBLK, 256, 0, stream>>>(k, v, mask, img, packed, CONVBLK);
    sattn_fast13<<<NBATCH * NH * (SLEN / 128), 256, 0, stream>>>(q, packed, img, out);
  } else {
    prep_kernel<<<PACKBLK, 256, 0, stream>>>(k, v, mask, nullptr, packed, 0);
    sattn_fallback<<<NBATCH * NH * (SLEN / 64), 256, 0, stream>>>(q, k, v, packed, out);
  }
}

// Round 16
// 65.940 us; speedup vs baseline: 1.1022x; 1.0115x over previous
//
#include <hip/hip_runtime.h>
#include <hip/hip_bf16.h>
#include <math.h>

// SparseFlashAttention: B=2, S=2048, H=16, D=64, fp32 in/out, [S,S] bool mask.
#define SLEN 2048
#define NBATCH 2
#define NH 16
#define DH 64
#define WPR 64      // mask words per row
#define NROUND 32   // 64-key rounds
#define TILEB 16384 // bytes per 64-key fragment-image tile (K frags 0-7, V frags 8-15)
#define CONVBLK (NBATCH * NH * NROUND)          // 1024 conv blocks
#define PACKBLK (SLEN * WPR / 256)              // 512 pack blocks

typedef __attribute__((ext_vector_type(4))) short short4v;
typedef __attribute__((ext_vector_type(8))) short short8v;
typedef __attribute__((ext_vector_type(4))) float float4v;
typedef __attribute__((ext_vector_type(16))) float float16v;

typedef __attribute__((address_space(1))) void gas_void;
typedef __attribute__((address_space(3))) void las_void;

__device__ __forceinline__ unsigned short f2bf(float f) {
  unsigned u = __float_as_uint(f);
  u += 0x7fffu + ((u >> 16) & 1u);
  return (unsigned short)(u >> 16);
}

__device__ __forceinline__ float fexp2(float x) {
#if __has_builtin(__builtin_amdgcn_exp2f)
  return __builtin_amdgcn_exp2f(x);
#else
  return __expf(x * 0.6931471805599453f);
#endif
}

// RNE pack via integer ops (prep/Q path)
__device__ __forceinline__ unsigned pack_bf2(float a, float b) {
  unsigned ua = __float_as_uint(a); ua += 0x7fffu + ((ua >> 16) & 1u);
  unsigned ub = __float_as_uint(b); ub += 0x7fffu + ((ub >> 16) & 1u);
  return __builtin_amdgcn_perm(ub, ua, 0x07060302u);
}

// HW packed f32->bf16x2: dst[15:0]=bf16(lo), dst[31:16]=bf16(hi). 1 VALU op.
__device__ __forceinline__ unsigned cvtpk(float lo, float hi) {
  unsigned r;
  asm("v_cvt_pk_bf16_f32 %0, %1, %2" : "=v"(r) : "v"(lo), "v"(hi));
  return r;
}

// bool-byte word (bytes in {0,1}) -> 4-bit nibble, bit j = byte j
__device__ __forceinline__ unsigned nib4(unsigned w) {
  return ((w * 0x01020408u) >> 24) & 0xFu;
}

// ---------------------------------------------------------------------------
// Fragment-image layout (verified R9): tile (bh, t) = 16 frags x 1024 B.
// Lane l of frag i reads bytes [i*1024 + l*16, +16) -- coalesced per wave.
//   K element (key r, dim d):  frag = (r>>5)*4 + (d>>4);
//     lane = ((d>>3)&1)*32 + (r&31); byte slot = (d&7)*2.
//   V element (key p, dim d):  frag = 8 + (d>>5)*4 + 2*(p>>5) + ((p>>4)&1);
//     lane = ((p>>2)&1)*32 + (d&31); slot = (4*((p>>3)&1) + (p&3))*2.
// V path stages through LDS so global writes are coalesced 16B (R15).
// ---------------------------------------------------------------------------
__global__ __launch_bounds__(256) void prep_kernel(
    const float* __restrict__ kk, const float* __restrict__ vv,
    const void* __restrict__ mask,
    char* __restrict__ img, unsigned* __restrict__ packed, int convblocks) {
  const int tid = threadIdx.x;
  if (blockIdx.x >= convblocks) {  // ---- mask pack with block-local self-detect
    const int w = (blockIdx.x - convblocks) * 256 + tid;
    const uint4* bp = (const uint4*)((const char*)mask + (size_t)w * 32);
    uint4 x = bp[0], y = bp[1];
    const unsigned orw = (x.x | x.y) | (x.z | x.w) | (y.x | y.y) | (y.z | y.w);
    __shared__ int s0, sm;
    if (tid == 0) { s0 = 0; sm = 0; }
    __syncthreads();
    const int lane0 = ((tid & 63) == 0);
    if (__any((orw & 0x000000ffu) != 0) && lane0) atomicOr(&s0, 1);
    if (__any((orw & 0xffffff00u) != 0) && lane0) atomicOr(&sm, 1);
    __syncthreads();
    unsigned bits;
    if (s0 && sm) {  // byte bools
      bits = nib4(x.x) | (nib4(x.y) << 4) | (nib4(x.z) << 8) | (nib4(x.w) << 12) |
             (nib4(y.x) << 16) | (nib4(y.y) << 20) | (nib4(y.z) << 24) | (nib4(y.w) << 28);
    } else {  // 32-bit words
      const unsigned* m = (const unsigned*)mask + (size_t)w * 32;
      bits = 0u;
#pragma unroll
      for (int j = 0; j < 32; j++) bits |= (m[j] ? 1u : 0u) << j;
    }
    packed[w] = bits;
    return;
  }
  // ---- conv (fragment images)
  const int bid = blockIdx.x;  // bh*32 + t
  const int t = bid & 31;
  const int bh = bid >> 5;
  const int b = bh >> 4, h = bh & 15;
  char* timg = img + (size_t)bid * TILEB;

  {  // K: thread -> (key r, 16-dim group dg); two 16B contiguous writes
    const int r = tid >> 2;
    const int dg = (tid & 3) << 4;
    const float* src = kk + (((size_t)(b * SLEN + t * 64 + r) * NH + h) * DH + dg);
    const int f = ((r >> 5) << 2) + (dg >> 4);
    char* base = timg + f * 1024 + (r & 31) * 16;  // hl=0 slot; hl=1 at +512
    float4v x0 = *(const float4v*)(src);
    float4v x1 = *(const float4v*)(src + 4);
    float4v x2 = *(const float4v*)(src + 8);
    float4v x3 = *(const float4v*)(src + 12);
    union { unsigned u[4]; short8v s8; } lo, hi;
    lo.u[0] = pack_bf2(x0.x, x0.y); lo.u[1] = pack_bf2(x0.z, x0.w);
    lo.u[2] = pack_bf2(x1.x, x1.y); lo.u[3] = pack_bf2(x1.z, x1.w);
    hi.u[0] = pack_bf2(x2.x, x2.y); hi.u[1] = pack_bf2(x2.z, x2.w);
    hi.u[2] = pack_bf2(x3.x, x3.y); hi.u[3] = pack_bf2(x3.z, x3.w);
    *(short8v*)(base) = lo.s8;
    *(short8v*)(base + 512) = hi.s8;
  }
  {  // V: coalesced f32 reads -> bf16 LDS [key][d] (stride 68) -> coalesced
    // 16B fragment-cell stores.
    __shared__ unsigned short vlds[64 * 68];
    const int key = tid >> 2;
    const int dg = (tid & 3) << 4;
    const float* src = vv + (((size_t)(b * SLEN + t * 64 + key) * NH + h) * DH + dg);
    unsigned short* lp = vlds + key * 68 + dg;
#pragma unroll
    for (int i = 0; i < 4; i++) {
      float4v x = *(const float4v*)(src + i * 4);
      union { unsigned u[2]; short4v s4; } cv;
      cv.u[0] = pack_bf2(x.x, x.y);
      cv.u[1] = pack_bf2(x.z, x.w);
      *(short4v*)(lp + i * 4) = cv.s4;
    }
    __syncthreads();
#pragma unroll
    for (int c = 0; c < 2; c++) {
      const int cell = c * 256 + tid;    // consecutive tid -> consecutive 16B
      const int fp = cell >> 6;          // 0..7 (frag = 8 + fp)
      const int lane16 = cell & 63;
      const int d = ((fp >> 2) & 1) * 32 + (lane16 & 31);
      const int pbase = 32 * ((fp >> 1) & 1) + 16 * (fp & 1) + 4 * (lane16 >> 5);
      union { unsigned short s[8]; short8v v8; } w;
#pragma unroll
      for (int slot = 0; slot < 8; slot++) {
        const int p = pbase + 8 * (slot >> 2) + (slot & 3);
        w.s[slot] = vlds[p * 68 + d];
      }
      *(short8v*)(timg + (8 + fp) * 1024 + lane16 * 16) = w.v8;
    }
  }
}

// ---------------------------------------------------------------------------
// Main kernel R16: 8-deep LDS tile ring, barrier per 4 rounds.
// 256 blocks x 512 threads (8 waves = 1 block/CU); each wave owns 32 queries.
// Rationale: no-LDS variants are TA-request-bound (16 dwordx4/wave/round ~90%
// TA); per-round-barrier LDS variants are barrier-drain-bound. This variant
// stages via global_load_lds (TA ~11%) AND amortizes the vmcnt(0)+barrier
// over 4 tiles (8 barriers total vs 32). Ring: group g computes tiles
// 4g..4g+3 from buffers (g&1)*4+u while loads for 4g+4..4g+7 fill the other
// half; barrier at group end. Compute body = R14's verified code (bit-mask
// softmax, cvtpk, 32x32x16 MFMAs, VALU lsum), fragments via ds_read_b128.
// ---------------------------------------------------------------------------
__global__ __launch_bounds__(512, 2) void sattn_fast14(
    const float* __restrict__ q, const unsigned* __restrict__ pmask,
    const char* __restrict__ img, float* __restrict__ out) {
  __shared__ __align__(16) char ring[8 * TILEB];  // 128 KB

  const int tid = threadIdx.x;
  const int xcd = blockIdx.x & 7;
  const int j = blockIdx.x >> 3;            // 0..31
  const int bh = xcd * 4 + (j >> 3);        // 4 bh per XCD -> images L2-resident
  const int chunk = j & 7;                  // 8 chunks of 256 queries
  const int b = bh >> 4;
  const int hd = bh & 15;
  const int wave = tid >> 6;                // 0..7
  const int lane = tid & 63;
  const int l31 = lane & 31;
  const int hl = lane >> 5;

  const int qrow = chunk * 256 + wave * 32 + l31;
  const int qw = qrow * WPR;

  // Q B-frags, pre-scaled by (1/sqrt(64))*log2(e); qf[ds] elem j = Q[q][16ds+8hl+j]
  const float SCL2 = 0.18033688011112042f;
  short8v qf[4];
  {
    const float* qp = q + (((size_t)b * SLEN + qrow) * NH + hd) * DH;
#pragma unroll
    for (int ds = 0; ds < 4; ds++) {
      float4v x0 = *(const float4v*)(qp + ds * 16 + hl * 8);
      float4v x1 = *(const float4v*)(qp + ds * 16 + hl * 8 + 4);
      union { unsigned u[4]; short8v s8; } cv;
      cv.u[0] = pack_bf2(x0.x * SCL2, x0.y * SCL2);
      cv.u[1] = pack_bf2(x0.z * SCL2, x0.w * SCL2);
      cv.u[2] = pack_bf2(x1.x * SCL2, x1.y * SCL2);
      cv.u[3] = pack_bf2(x1.z * SCL2, x1.w * SCL2);
      qf[ds] = cv.s8;
    }
  }

  const char* gimg = img + (size_t)bh * (NROUND * TILEB) + tid * 16;

  float16v acc0 = {}, acc1 = {};
  float lsum = 0.f;

  // prologue: stage tiles 0..3 into ring buffers 0..3
#pragma unroll
  for (int i = 0; i < 4; i++) {
    char* dst = &ring[i * TILEB] + tid * 16;
    const char* src = gimg + (size_t)i * TILEB;
    __builtin_amdgcn_global_load_lds((gas_void*)(src), (las_void*)(dst), 16, 0, 0);
    __builtin_amdgcn_global_load_lds((gas_void*)(src + 8192), (las_void*)(dst + 8192), 16, 0, 0);
  }
  __syncthreads();

  for (int g = 0; g < 8; g++) {
    // ---- issue prefetch for tiles 4g+4..4g+7 into the other ring half
    if (g < 7) {
      const int dstbase = ((g + 1) & 1) * 4;
#pragma unroll
      for (int i = 0; i < 4; i++) {
        const int tn = 4 * g + 4 + i;
        char* dst = &ring[(dstbase + i) * TILEB] + tid * 16;
        const char* src = gimg + (size_t)tn * TILEB;
        __builtin_amdgcn_global_load_lds((gas_void*)(src), (las_void*)(dst), 16, 0, 0);
        __builtin_amdgcn_global_load_lds((gas_void*)(src + 8192), (las_void*)(dst + 8192), 16, 0, 0);
      }
    }

    // ---- compute 4 rounds from this ring half
#pragma unroll
    for (int u = 0; u < 4; u++) {
      const int t = 4 * g + u;
      const char* Kl = &ring[((g & 1) * 4 + u) * TILEB] + lane * 16;
      const char* Vl = Kl + 8192;
      const uint2 m = *(const uint2*)&pmask[qw + 2 * t];
      const unsigned m0 = m.x, m1 = m.y;

      short8v kf0 = *(const short8v*)(Kl + 0);
      short8v kf1 = *(const short8v*)(Kl + 1024);
      short8v kf2 = *(const short8v*)(Kl + 2048);
      short8v kf3 = *(const short8v*)(Kl + 3072);
      short8v kf4 = *(const short8v*)(Kl + 4096);
      short8v kf5 = *(const short8v*)(Kl + 5120);
      short8v kf6 = *(const short8v*)(Kl + 6144);
      short8v kf7 = *(const short8v*)(Kl + 7168);

      __builtin_amdgcn_s_setprio(1);
      float16v st0 = {}, st1 = {};
      st0 = __builtin_amdgcn_mfma_f32_32x32x16_bf16(kf0, qf[0], st0, 0, 0, 0);
      st1 = __builtin_amdgcn_mfma_f32_32x32x16_bf16(kf4, qf[0], st1, 0, 0, 0);
      st0 = __builtin_amdgcn_mfma_f32_32x32x16_bf16(kf1, qf[1], st0, 0, 0, 0);
      st1 = __builtin_amdgcn_mfma_f32_32x32x16_bf16(kf5, qf[1], st1, 0, 0, 0);
      st0 = __builtin_amdgcn_mfma_f32_32x32x16_bf16(kf2, qf[2], st0, 0, 0, 0);
      st1 = __builtin_amdgcn_mfma_f32_32x32x16_bf16(kf6, qf[2], st1, 0, 0, 0);
      st0 = __builtin_amdgcn_mfma_f32_32x32x16_bf16(kf3, qf[3], st0, 0, 0, 0);
      st1 = __builtin_amdgcn_mfma_f32_32x32x16_bf16(kf7, qf[3], st1, 0, 0, 0);
      __builtin_amdgcn_s_setprio(0);

      // ---- softmax + mask + pack (verified bit-mask path)
      // reg r of st_h <-> key 32h + (r&3) + 8*(r>>2) + 4*hl
      float p0[16], p1[16];
#pragma unroll
      for (int uu = 0; uu < 4; uu++) {
        const unsigned hw0 = m0 >> (8 * uu + 4 * hl);
        const unsigned hw1 = m1 >> (8 * uu + 4 * hl);
        {
          float a0 = fexp2(st0[4 * uu + 0]); a0 = (hw0 & 1u) ? a0 : 0.f;
          float a1 = fexp2(st0[4 * uu + 1]); a1 = (hw0 & 2u) ? a1 : 0.f;
          float a2 = fexp2(st0[4 * uu + 2]); a2 = (hw0 & 4u) ? a2 : 0.f;
          float a3 = fexp2(st0[4 * uu + 3]); a3 = (hw0 & 8u) ? a3 : 0.f;
          lsum += (a0 + a1) + (a2 + a3);
          p0[4 * uu + 0] = a0; p0[4 * uu + 1] = a1; p0[4 * uu + 2] = a2; p0[4 * uu + 3] = a3;
        }
        {
          float a0 = fexp2(st1[4 * uu + 0]); a0 = (hw1 & 1u) ? a0 : 0.f;
          float a1 = fexp2(st1[4 * uu + 1]); a1 = (hw1 & 2u) ? a1 : 0.f;
          float a2 = fexp2(st1[4 * uu + 2]); a2 = (hw1 & 4u) ? a2 : 0.f;
          float a3 = fexp2(st1[4 * uu + 3]); a3 = (hw1 & 8u) ? a3 : 0.f;
          lsum += (a0 + a1) + (a2 + a3);
          p1[4 * uu + 0] = a0; p1[4 * uu + 1] = a1; p1[4 * uu + 2] = a2; p1[4 * uu + 3] = a3;
        }
      }
      short8v pf0, pf1, pf2, pf3;
      {
        union { unsigned u[4]; short8v s8; } c0, c1, c2, c3;
#pragma unroll
        for (int jj = 0; jj < 4; jj++) {
          c0.u[jj] = cvtpk(p0[2 * jj], p0[2 * jj + 1]);
          c1.u[jj] = cvtpk(p0[8 + 2 * jj], p0[8 + 2 * jj + 1]);
          c2.u[jj] = cvtpk(p1[2 * jj], p1[2 * jj + 1]);
          c3.u[jj] = cvtpk(p1[8 + 2 * jj], p1[8 + 2 * jj + 1]);
        }
        pf0 = c0.s8; pf1 = c1.s8; pf2 = c2.s8; pf3 = c3.s8;
      }

      // ---- PV (V-frag kc for d-half n at Vl + (n*4+kc)*1024)
      short8v vf0 = *(const short8v*)(Vl + 0);
      short8v vf1 = *(const short8v*)(Vl + 1024);
      short8v vf2 = *(const short8v*)(Vl + 2048);
      short8v vf3 = *(const short8v*)(Vl + 3072);
      short8v vf4 = *(const short8v*)(Vl + 4096);
      short8v vf5 = *(const short8v*)(Vl + 5120);
      short8v vf6 = *(const short8v*)(Vl + 6144);
      short8v vf7 = *(const short8v*)(Vl + 7168);
      __builtin_amdgcn_s_setprio(1);
      acc0 = __builtin_amdgcn_mfma_f32_32x32x16_bf16(vf0, pf0, acc0, 0, 0, 0);
      acc1 = __builtin_amdgcn_mfma_f32_32x32x16_bf16(vf4, pf0, acc1, 0, 0, 0);
      acc0 = __builtin_amdgcn_mfma_f32_32x32x16_bf16(vf1, pf1, acc0, 0, 0, 0);
      acc1 = __builtin_amdgcn_mfma_f32_32x32x16_bf16(vf5, pf1, acc1, 0, 0, 0);
      acc0 = __builtin_amdgcn_mfma_f32_32x32x16_bf16(vf2, pf2, acc0, 0, 0, 0);
      acc1 = __builtin_amdgcn_mfma_f32_32x32x16_bf16(vf6, pf2, acc1, 0, 0, 0);
      acc0 = __builtin_amdgcn_mfma_f32_32x32x16_bf16(vf3, pf3, acc0, 0, 0, 0);
      acc1 = __builtin_amdgcn_mfma_f32_32x32x16_bf16(vf7, pf3, acc1, 0, 0, 0);
      __builtin_amdgcn_s_setprio(0);
    }

    // one barrier per 4 rounds: drains this group's prefetch (issued ~4 rounds
    // ago -> long latency fully hidden) and fences buffer reuse.
    __syncthreads();
  }

  // q = l31 row total = this lane's partial + the other hl's partial
  lsum += __shfl_xor(lsum, 32);
  const float inv = (lsum > 0.f) ? 1.f / lsum : 0.f;
  float* op = out + (((size_t)b * SLEN + qrow) * NH + hd) * DH;
#pragma unroll
  for (int u = 0; u < 4; u++) {
    float4v o0, o1;
    o0.x = acc0[4 * u + 0] * inv; o0.y = acc0[4 * u + 1] * inv;
    o0.z = acc0[4 * u + 2] * inv; o0.w = acc0[4 * u + 3] * inv;
    o1.x = acc1[4 * u + 0] * inv; o1.y = acc1[4 * u + 1] * inv;
    o1.z = acc1[4 * u + 2] * inv; o1.w = acc1[4 * u + 3] * inv;
    *(float4v*)(op + 8 * u + 4 * hl) = o0;
    *(float4v*)(op + 32 + 8 * u + 4 * hl) = o1;
  }
}

// ---------------------------------------------------------------------------
// Fallback (R1 kernel, verified): used only if ws_size can't hold the images.
// ---------------------------------------------------------------------------
__global__ __launch_bounds__(256) void sattn_fallback(
    const float* __restrict__ q, const float* __restrict__ kk,
    const float* __restrict__ vv, const unsigned int* __restrict__ pmask,
    float* __restrict__ out) {
  __shared__ __align__(16) unsigned short Kt[16 * 64];
  __shared__ __align__(16) unsigned short Vt[64 * 20];

  const int tid = threadIdx.x;
  const int chunk = blockIdx.x & 31;
  const int bh = blockIdx.x >> 5;
  const int b = bh >> 4;
  const int h = bh & 15;
  const int wave = tid >> 6;
  const int lane = tid & 63;
  const int lq = lane & 15;
  const int g = lane >> 4;

  const int qrow = chunk * 64 + wave * 16 + lq;

  short4v qf[4];
  {
    const float* qp = q + (((size_t)b * SLEN + qrow) * NH + h) * DH;
#pragma unroll
    for (int ks = 0; ks < 4; ks++) {
      float4v x = *(const float4v*)(qp + ks * 16 + g * 4);
      short4v s;
      s.x = (short)f2bf(x.x); s.y = (short)f2bf(x.y);
      s.z = (short)f2bf(x.z); s.w = (short)f2bf(x.w);
      qf[ks] = s;
    }
  }

  const int srow = tid >> 4;
  const int scol = (tid & 15) * 4;
  const size_t kvbase = (size_t)b * SLEN * (NH * DH) + (size_t)h * DH;

  float4v acc[4] = {};
  float m_run = -INFINITY;
  float l_run = 0.f;

  for (int t = 0; t < SLEN / 16; t++) {
    const int kbase = t * 16;
    __syncthreads();
    {
      const size_t rowoff = kvbase + (size_t)(kbase + srow) * (NH * DH) + scol;
      float4v x = *(const float4v*)(kk + rowoff);
      short4v s;
      s.x = (short)f2bf(x.x); s.y = (short)f2bf(x.y);
      s.z = (short)f2bf(x.z); s.w = (short)f2bf(x.w);
      const int off = (scol * 2) ^ ((srow & 7) << 4);
      *(short4v*)((char*)Kt + srow * 128 + off) = s;

      float4v y = *(const float4v*)(vv + rowoff);
      Vt[(scol + 0) * 20 + srow] = f2bf(y.x);
      Vt[(scol + 1) * 20 + srow] = f2bf(y.y);
      Vt[(scol + 2) * 20 + srow] = f2bf(y.z);
      Vt[(scol + 3) * 20 + srow] = f2bf(y.w);
    }
    __syncthreads();

    float4v stv = {0.f, 0.f, 0.f, 0.f};
#pragma unroll
    for (int ks = 0; ks < 4; ks++) {
      const int off = ((ks * 16 + g * 4) * 2) ^ ((lq & 7) << 4);
      short4v kf = *(const short4v*)((const char*)Kt + lq * 128 + off);
      stv = __builtin_amdgcn_mfma_f32_16x16x16bf16_1k(kf, qf[ks], stv, 0, 0, 0);
    }

    const unsigned int mw = pmask[qrow * WPR + (kbase >> 5)];
    const int shift = (kbase & 16) + g * 4;
    float sc[4];
    float tmax = -INFINITY;
#pragma unroll
    for (int r = 0; r < 4; r++) {
      bool a = (mw >> (shift + r)) & 1u;
      sc[r] = a ? stv[r] * 0.125f : -INFINITY;
      tmax = fmaxf(tmax, sc[r]);
    }
    tmax = fmaxf(tmax, __shfl_xor(tmax, 16));
    tmax = fmaxf(tmax, __shfl_xor(tmax, 32));
    const float mnew = fmaxf(m_run, tmax);
    const float muse = (mnew > -1e37f) ? mnew : 0.f;
    const float alpha = __expf(m_run - muse);
    float p[4], tsum = 0.f;
#pragma unroll
    for (int r = 0; r < 4; r++) {
      p[r] = __expf(sc[r] - muse);
      tsum += p[r];
    }
    tsum += __shfl_xor(tsum, 16);
    tsum += __shfl_xor(tsum, 32);
    l_run = l_run * alpha + tsum;
    m_run = mnew;

    short4v pfv;
    pfv.x = (short)f2bf(p[0]); pfv.y = (short)f2bf(p[1]);
    pfv.z = (short)f2bf(p[2]); pfv.w = (short)f2bf(p[3]);

#pragma unroll
    for (int n = 0; n < 4; n++) {
      acc[n][0] *= alpha; acc[n][1] *= alpha;
      acc[n][2] *= alpha; acc[n][3] *= alpha;
      short4v vf = *(const short4v*)((const char*)Vt + ((n * 16 + lq) * 20 + g * 4) * 2);
      acc[n] = __builtin_amdgcn_mfma_f32_16x16x16bf16_1k(vf, pfv, acc[n], 0, 0, 0);
    }
  }

  const float inv = (l_run > 0.f) ? 1.f / l_run : 0.f;
  float* op = out + (((size_t)b * SLEN + qrow) * NH + h) * DH;
#pragma unroll
  for (int n = 0; n < 4; n++) {
    float4v o;
    o.x = acc[n][0] * inv; o.y = acc[n][1] * inv;
    o.z = acc[n][2] * inv; o.w = acc[n][3] * inv;
    *(float4v*)(op + n * 16 + g * 4) = o;
  }
}

extern "C" void kernel_launch(void* const* d_in, const int* in_sizes, int n_in,
                              void* d_out, int out_size, void* d_ws, size_t ws_size,
                              hipStream_t stream) {
  const float* q = (const float*)d_in[0];
  const float* k = (const float*)d_in[1];
  const float* v = (const float*)d_in[2];
  const void* mask = d_in[3];
  float* out = (float*)d_out;

  unsigned int* packed = (unsigned int*)((char*)d_ws + 256);   // 512 KB
  char* img = (char*)d_ws + (1 << 20);                         // 16 MB
  const size_t need = (size_t)(1 << 20) + (size_t)CONVBLK * TILEB;

  if (ws_size >= need) {
    prep_kernel<<<CONVBLK + PACKBLK, 256, 0, stream>>>(k, v, mask, img, packed, CONVBLK);
    sattn_fast14<<<NBATCH * NH * (SLEN / 256), 512, 0, stream>>>(q, packed, img, out);
  } else {
    prep_kernel<<<PACKBLK, 256, 0, stream>>>(k, v, mask, nullptr, packed, 0);
    sattn_fallback<<<NBATCH * NH * (SLEN / 64), 256, 0, stream>>>(q, k, v, packed, out);
  }
}